// Round 3
// baseline (406.935 us; speedup 1.0000x reference)
//
#include <hip/hip_runtime.h>
#include <hip/hip_bf16.h>
#include <cstdint>
#include <cstddef>

#define T0_ 512
#define TT_ 2048
#define WD_ 2048
#define NH_ 16
#define KH_ 4

typedef __attribute__((ext_vector_type(8))) short short8;
typedef __attribute__((ext_vector_type(4))) short short4v;
typedef __attribute__((ext_vector_type(4))) float f32x4;

#define AS1 __attribute__((address_space(1)))
#define AS3 __attribute__((address_space(3)))

__device__ __forceinline__ ushort f2bf(float x) {
  __hip_bfloat16 h = __float2bfloat16(x);
  ushort u; __builtin_memcpy(&u, &h, 2); return u;
}
__device__ __forceinline__ float bf2f(ushort u) {
  __hip_bfloat16 h; __builtin_memcpy(&h, &u, 2);
  return __bfloat162float(h);
}
__device__ __forceinline__ void g2l16(const ushort* g, AS3 ushort* s) {
  __builtin_amdgcn_global_load_lds((const AS1 uint32_t*)g, (AS3 uint32_t*)s, 16, 0, 0);
}

// ---------------------------------------------------------------------------
// x0/x1 (f32) -> xb (2048x2048 bf16)
__global__ __launch_bounds__(256) void convert_x(
    const float* __restrict__ x0, const float* __restrict__ x1, ushort* __restrict__ xb)
{
  const int i = blockIdx.x * 256 + threadIdx.x;
  const int e = i * 4;
  const int row = e >> 11, col = e & 2047;
  const float* src = (row < T0_) ? (x0 + (size_t)row * WD_ + col)
                                 : (x1 + (size_t)(row - T0_) * WD_ + col);
  const float4 v = *(const float4*)src;
  ushort4 o; o.x = f2bf(v.x); o.y = f2bf(v.y); o.z = f2bf(v.z); o.w = f2bf(v.w);
  *(ushort4*)(xb + e) = o;
}

// ---------------------------------------------------------------------------
// Transpose-convert: in f32 (slab,R,C) -> out bf16 (slab,C,R)
__global__ __launch_bounds__(256) void convtrans(
    const float* __restrict__ in, ushort* __restrict__ out, int R, int C)
{
  __shared__ float tile[32][33];
  const int z = blockIdx.z;
  in  += (size_t)z * R * C;
  out += (size_t)z * R * C;
  const int r0 = blockIdx.x * 32, c0 = blockIdx.y * 32;
  const int tx = threadIdx.x & 31, ty = threadIdx.x >> 5;
#pragma unroll
  for (int i = 0; i < 4; ++i)
    tile[ty + 8 * i][tx] = in[(size_t)(r0 + ty + 8 * i) * C + c0 + tx];
  __syncthreads();
#pragma unroll
  for (int i = 0; i < 4; ++i)
    out[(size_t)(c0 + ty + 8 * i) * R + r0 + tx] = f2bf(tile[tx][ty + 8 * i]);
}

// Dual-source variant: z < half -> s0/d0 slab z, else s1/d1 slab z-half.
__global__ __launch_bounds__(256) void convtrans2(
    const float* __restrict__ s0, const float* __restrict__ s1,
    ushort* __restrict__ d0, ushort* __restrict__ d1, int R, int C, int half)
{
  __shared__ float tile[32][33];
  int z = blockIdx.z;
  const float* in; ushort* out;
  if (z < half) { in = s0 + (size_t)z * R * C; out = d0 + (size_t)z * R * C; }
  else { z -= half; in = s1 + (size_t)z * R * C; out = d1 + (size_t)z * R * C; }
  const int r0 = blockIdx.x * 32, c0 = blockIdx.y * 32;
  const int tx = threadIdx.x & 31, ty = threadIdx.x >> 5;
#pragma unroll
  for (int i = 0; i < 4; ++i)
    tile[ty + 8 * i][tx] = in[(size_t)(r0 + ty + 8 * i) * C + c0 + tx];
  __syncthreads();
#pragma unroll
  for (int i = 0; i < 4; ++i)
    out[(size_t)(c0 + ty + 8 * i) * R + r0 + tx] = f2bf(tile[tx][ty + 8 * i]);
}

// ---------------------------------------------------------------------------
// Shared MFMA GEMM core: 128x128 C tile, BK=64, 256 thr (4 waves 2x2).
// T4 counted-vmcnt pipeline: 3 LDS buffers, depth-2 prefetch, raw s_barrier,
// s_waitcnt vmcnt(8) in steady state (NEVER 0 in the main loop). Each stage
// gets ~2 iterations to land -> HBM/L2 latency hidden within-wave (occupancy
// counters show ~1 block/CU, so inter-block overlap can't do it).
// Hazards: write-after-read guarded by the one barrier per iter (all waves
// pass it only after compute(t-1)'s lgkm-waited reads); read-after-DMA by
// per-wave vmcnt(8) BEFORE the barrier; asm "memory" clobber stops ds_read
// hoisting above the wait.
// LDS chunk-XOR swizzle (kept from prev round, conflicts measured 0):
// write side pre-swizzles the GLOBAL chunk, read side slot = chunk ^ (lm&7).
__device__ __forceinline__ void gemm_core(
    const ushort* __restrict__ A, const ushort* __restrict__ Bt,
    int row0, int col0, ushort* As, ushort* Bs, f32x4 (&acc)[4][4])
{
  const int tid = threadIdx.x;
  const int w = tid >> 6, l = tid & 63, lq = l >> 4, lm = l & 15;
  const int wr = (w >> 1) * 64, wc = (w & 1) * 64;
  const int sx = lm & 7;                               // read-swizzle key
  const int gsw = (tid & 7) ^ ((tid >> 3) & 7);        // pre-swizzled source chunk
  const ushort* Ag = A + (size_t)(row0 + (tid >> 3)) * WD_ + gsw * 8;
  const ushort* Bg = Bt + (size_t)(col0 + (tid >> 3)) * WD_ + gsw * 8;
  AS3 ushort* AsW = (AS3 ushort*)As + w * 512;   // wave w: rows w*8 + c*32
  AS3 ushort* BsW = (AS3 ushort*)Bs + w * 512;

  auto stage = [&](int buf, int k0) {
#pragma unroll
    for (int c = 0; c < 4; ++c) {
      g2l16(Ag + (size_t)(c * 32) * WD_ + k0, AsW + buf * 8192 + c * 2048);
      g2l16(Bg + (size_t)(c * 32) * WD_ + k0, BsW + buf * 8192 + c * 2048);
    }
  };

  const int NT = WD_ / 64;        // 32 K-steps
  stage(0, 0);
  stage(1, 64);                    // 16 loads in flight per wave
  int rb = 0, sb = 2;
  for (int t = 0; t < NT; ++t) {
    if (t + 1 < NT) asm volatile("s_waitcnt vmcnt(8)" ::: "memory");
    else            asm volatile("s_waitcnt vmcnt(0)" ::: "memory");
    __builtin_amdgcn_s_barrier();
    if (t + 2 < NT) { stage(sb, (t + 2) * 64); sb = (sb == 2) ? 0 : sb + 1; }
    const ushort* Ab = As + rb * 8192;
    const ushort* Bb = Bs + rb * 8192;
    rb = (rb == 2) ? 0 : rb + 1;
#pragma unroll
    for (int kk = 0; kk < 2; ++kk) {
      short8 af[4], bfr[4];
#pragma unroll
      for (int mi = 0; mi < 4; ++mi)
        af[mi] = *(const short8*)&Ab[(wr + mi * 16 + lm) * 64 + (((kk * 4 + lq) ^ sx) << 3)];
#pragma unroll
      for (int ni = 0; ni < 4; ++ni)
        bfr[ni] = *(const short8*)&Bb[(wc + ni * 16 + lm) * 64 + (((kk * 4 + lq) ^ sx) << 3)];
      __builtin_amdgcn_s_setprio(1);
#pragma unroll
      for (int mi = 0; mi < 4; ++mi)
#pragma unroll
        for (int ni = 0; ni < 4; ++ni)
          acc[mi][ni] = __builtin_amdgcn_mfma_f32_16x16x32_bf16(af[mi], bfr[ni], acc[mi][ni], 0, 0, 0);
      __builtin_amdgcn_s_setprio(0);
    }
  }
}

// ---------------------------------------------------------------------------
// All projections in one launch. grid (40, 16):
//  bx<32: qg (bf16, ldc 4096) | bx 32..35: k->kcache f32 | bx 36..39: v->vcache f32
__global__ __launch_bounds__(256) void gemm_proj(
    const ushort* __restrict__ A,
    const ushort* __restrict__ qg0t, const ushort* __restrict__ qg1t,
    const ushort* __restrict__ k0t,  const ushort* __restrict__ k1t,
    const ushort* __restrict__ v0t,  const ushort* __restrict__ v1t,
    ushort* __restrict__ Cqg, float* __restrict__ kc, float* __restrict__ vc)
{
  __shared__ ushort As[24576], Bs[24576];
  const int bx = blockIdx.x;
  const int row0 = blockIdx.y * 128;
  const bool s1 = (row0 >= T0_);
  const ushort* Bt; int col0;
  float* Cf = nullptr; ushort* Cb = nullptr; int ldc;
  if (bx < 32) {
    Bt = s1 ? qg1t : qg0t; col0 = bx * 128; Cb = Cqg; ldc = 4096;
  } else if (bx < 36) {
    Bt = s1 ? k1t : k0t; col0 = (bx - 32) * 128; Cf = kc; ldc = 512;
  } else {
    Bt = s1 ? v1t : v0t; col0 = (bx - 36) * 128; Cf = vc; ldc = 512;
  }
  f32x4 acc[4][4];
#pragma unroll
  for (int mi = 0; mi < 4; ++mi)
#pragma unroll
    for (int ni = 0; ni < 4; ++ni) acc[mi][ni] = (f32x4){0.f, 0.f, 0.f, 0.f};
  gemm_core(A, Bt, row0, col0, As, Bs, acc);
  const int w = threadIdx.x >> 6, l = threadIdx.x & 63, lq = l >> 4, lm = l & 15;
  const int wr = (w >> 1) * 64, wc = (w & 1) * 64;
#pragma unroll
  for (int mi = 0; mi < 4; ++mi)
#pragma unroll
    for (int ni = 0; ni < 4; ++ni)
#pragma unroll
      for (int r = 0; r < 4; ++r) {
        const size_t rr = (size_t)row0 + wr + mi * 16 + lq * 4 + r;
        const size_t cc = (size_t)col0 + wc + ni * 16 + lm;
        if (Cb) Cb[rr * ldc + cc] = f2bf(acc[mi][ni][r]);
        else    Cf[rr * ldc + cc] = acc[mi][ni][r];
      }
}

// out projection: grid (16, 16); C f32 (t, 2048), weight by stream.
__global__ __launch_bounds__(256) void gemm_out(
    const ushort* __restrict__ A, const ushort* __restrict__ W0t,
    const ushort* __restrict__ W1t, float* __restrict__ C)
{
  __shared__ ushort As[24576], Bs[24576];
  const int row0 = blockIdx.y * 128, col0 = blockIdx.x * 128;
  const ushort* Bt = (row0 < T0_) ? W0t : W1t;
  f32x4 acc[4][4];
#pragma unroll
  for (int mi = 0; mi < 4; ++mi)
#pragma unroll
    for (int ni = 0; ni < 4; ++ni) acc[mi][ni] = (f32x4){0.f, 0.f, 0.f, 0.f};
  gemm_core(A, Bt, row0, col0, As, Bs, acc);
  const int w = threadIdx.x >> 6, l = threadIdx.x & 63, lq = l >> 4, lm = l & 15;
  const int wr = (w >> 1) * 64, wc = (w & 1) * 64;
#pragma unroll
  for (int mi = 0; mi < 4; ++mi)
#pragma unroll
    for (int ni = 0; ni < 4; ++ni)
#pragma unroll
      for (int r = 0; r < 4; ++r) {
        const size_t rr = (size_t)row0 + wr + mi * 16 + lq * 4 + r;
        const size_t cc = (size_t)col0 + wc + ni * 16 + lm;
        C[rr * 2048 + cc] = acc[mi][ni][r];
      }
}

// ---------------------------------------------------------------------------
// RMSNorm + RoPE (+ q scale).
__global__ __launch_bounds__(256) void postproc(
    ushort* __restrict__ qgb, float* __restrict__ kc, ushort* __restrict__ Kb,
    const int* __restrict__ positions,
    const float* __restrict__ qn0, const float* __restrict__ kn0,
    const float* __restrict__ qn1, const float* __restrict__ kn1)
{
  const int t = blockIdx.x;
  const int w = threadIdx.x >> 6, l = threadIdx.x & 63;
  const float pos = (float)positions[t];
  const bool str1 = (t >= T0_);
  const float* qn = str1 ? qn1 : qn0;
  const float* kn = str1 ? kn1 : kn0;
  const float kfreq = 13.815510557964274f / 32.0f;  // ln(1e6)/32
  const int h0 = 2 * l, h1 = 2 * l + 1;

  for (int r = w; r < NH_ + KH_; r += 4) {
    const bool isq = (r < NH_);
    float v0, v1; size_t bi; const float* sc;
    if (isq) {
      bi = ((size_t)t * NH_ + r) * 256;
      v0 = bf2f(qgb[bi + h0]); v1 = bf2f(qgb[bi + h1]); sc = qn;
    } else {
      bi = ((size_t)t * KH_ + (r - NH_)) * 128;
      v0 = kc[bi + h0]; v1 = kc[bi + h1]; sc = kn;
    }
    float ss = v0 * v0 + v1 * v1;
#pragma unroll
    for (int off = 32; off > 0; off >>= 1) ss += __shfl_xor(ss, off);
    const float rstd = rsqrtf(ss * (1.0f / 128.0f) + 1e-6f);
    v0 = v0 * rstd * (1.0f + sc[h0]);
    v1 = v1 * rstd * (1.0f + sc[h1]);
    const float p0 = __shfl_xor(v0, 16);
    const float p1 = __shfl_xor(v1, 16);
    if (l < 32) {
      const int i0 = (l < 16) ? h0 : (h0 - 32);
      const float a0 = pos * __expf(-(float)i0 * kfreq);
      const float a1 = pos * __expf(-(float)(i0 + 1) * kfreq);
      const float c0 = cosf(a0), s0 = sinf(a0);
      const float c1 = cosf(a1), s1v = sinf(a1);
      if (l < 16) { v0 = v0 * c0 - p0 * s0; v1 = v1 * c1 - p1 * s1v; }
      else        { v0 = v0 * c0 + p0 * s0; v1 = v1 * c1 + p1 * s1v; }
    }
    if (isq) {
      v0 *= 0.08838834764831843f; v1 *= 0.08838834764831843f;
      qgb[bi + h0] = f2bf(v0); qgb[bi + h1] = f2bf(v1);
    } else {
      kc[bi + h0] = v0; kc[bi + h1] = v1;
      Kb[bi + h0] = f2bf(v0); Kb[bi + h1] = f2bf(v1);
    }
  }
}

// ---------------------------------------------------------------------------
// Flash attention, S^T formulation, XOR-swizzled LDS, balanced qt-pairs.
// Block (bx, n): tiles qt = bx and qt = 31-bx (64 q rows each), 128-s K/V steps.
// qgb: normed q + raw gate bf16 (t,n,256); Kb (t,kh,128); Vt (kh,128,2048).
__global__ __launch_bounds__(256) void attn(
    const ushort* __restrict__ qgb, const ushort* __restrict__ Kb,
    const ushort* __restrict__ Vt, ushort* __restrict__ encb)
{
  __shared__ ushort Ks[2 * 16384];  // [buf][s 0..127][h 0..127], 16B chunks ^ (s&15)
  __shared__ ushort Vs[2 * 16384];  // [buf][h 0..127][s 0..127], 16B chunks ^ (h&15)
  __shared__ ushort Ps[4 * 2048];   // per-wave [q 0..15][s 0..127], 8B units ^ lm
  const int tid = threadIdx.x;
  const int w = tid >> 6, l = tid & 63, lq = l >> 4, lm = l & 15;
  const int n = blockIdx.y, kh = n >> 2;

  auto stage = [&](int buf, int s0) {
#pragma unroll
    for (int c = 0; c < 8; ++c) {
      const int row = w * 32 + c * 4 + lq;
      const int ch = lm ^ (row & 15);
      const int dst = buf * 16384 + (w * 32 + c * 4) * 128;
      g2l16(Kb + (size_t)(s0 + row) * 512 + kh * 128 + ch * 8, (AS3 ushort*)Ks + dst);
      g2l16(Vt + (size_t)(kh * 128 + row) * 2048 + s0 + ch * 8, (AS3 ushort*)Vs + dst);
    }
  };

  for (int half = 0; half < 2; ++half) {
    const int qt = half ? (31 - (int)blockIdx.x) : (int)blockIdx.x;
    const int qtb = qt * 64;
    const int nst = qt / 2 + 1;

    short8 aq[4];
    {
      const ushort* qb = qgb + ((size_t)(qtb + w * 16 + lm) * NH_ + n) * 256 + lq * 8;
#pragma unroll
      for (int kk = 0; kk < 4; ++kk) aq[kk] = *(const short8*)(qb + kk * 32);
    }
    f32x4 acc[8];
#pragma unroll
    for (int i = 0; i < 8; ++i) acc[i] = (f32x4){0.f, 0.f, 0.f, 0.f};
    float mq = -3.0e38f, lsum = 0.0f;  // softmax state for q = qtb + w*16 + lm

    __syncthreads();  // prior tile's LDS reads complete
    stage(0, 0);

    for (int st = 0; st < nst; ++st) {
      const int buf = st & 1;
      const int s0 = st * 128;
      __syncthreads();  // stage(st) visible
      if (st + 1 < nst) stage(buf ^ 1, s0 + 128);
      const ushort* Kt = Ks + buf * 16384;
      const ushort* Vb = Vs + buf * 16384;

      // S^T = K * Q^T : D[m=s][n=q]
      f32x4 sa[8];
#pragma unroll
      for (int mi = 0; mi < 8; ++mi) sa[mi] = (f32x4){0.f, 0.f, 0.f, 0.f};
#pragma unroll
      for (int kk = 0; kk < 4; ++kk)
#pragma unroll
        for (int mi = 0; mi < 8; ++mi) {
          const short8 ak = *(const short8*)&Kt[(mi * 16 + lm) * 128 + ((kk * 4 + lq) ^ lm) * 8];
          sa[mi] = __builtin_amdgcn_mfma_f32_16x16x32_bf16(ak, aq[kk], sa[mi], 0, 0, 0);
        }
      // causal mask: s > q -> -inf
      if (s0 + 127 > qtb) {
        const int qg_ = qtb + w * 16 + lm;
#pragma unroll
        for (int mi = 0; mi < 8; ++mi)
#pragma unroll
          for (int r = 0; r < 4; ++r)
            if (s0 + mi * 16 + lq * 4 + r > qg_) sa[mi][r] = -3.0e38f;
      }
      // online softmax over s (in-lane 32 vals + 2 shfl levels)
      float mx = sa[0][0];
#pragma unroll
      for (int mi = 0; mi < 8; ++mi)
#pragma unroll
        for (int r = 0; r < 4; ++r) mx = fmaxf(mx, sa[mi][r]);
      mx = fmaxf(mx, __shfl_xor(mx, 16));
      mx = fmaxf(mx, __shfl_xor(mx, 32));
      const float mn = fmaxf(mq, mx);
      const float alpha = __expf(mq - mn);
      mq = mn;
      float sl = 0.0f;
#pragma unroll
      for (int mi = 0; mi < 8; ++mi)
#pragma unroll
        for (int r = 0; r < 4; ++r) {
          const float p = __expf(sa[mi][r] - mn);
          sa[mi][r] = p; sl += p;
        }
      sl += __shfl_xor(sl, 16);
      sl += __shfl_xor(sl, 32);
      lsum = lsum * alpha + sl;

      // P -> per-wave LDS [q][s], bf16, 4-short units, unit index (s/4) ^ lm
#pragma unroll
      for (int mi = 0; mi < 8; ++mi) {
        short4v pw;
#pragma unroll
        for (int r = 0; r < 4; ++r) pw[r] = (short)f2bf(sa[mi][r]);
        *(short4v*)&Ps[w * 2048 + lm * 128 + (((mi * 4 + lq)) ^ lm) * 4] = pw;
      }
      // rescale acc (alpha for q = lq*4+r lives in lane lq*4+r)
      float aP[4];
#pragma unroll
      for (int r = 0; r < 4; ++r) aP[r] = __shfl(alpha, lq * 4 + r);
#pragma unroll
      for (int hi = 0; hi < 8; ++hi) {
        f32x4 a = acc[hi];
#pragma unroll
        for (int r = 0; r < 4; ++r) a[r] *= aP[r];
        acc[hi] = a;
      }
      // O += P V : A = P[q][s] from Ps (k-block mi2 needs s/4 units
      // mi2*8 + lq*2 + {0,1}), B = V[s][h] from Vs (s/8 unit mi2*4 + lq)
#pragma unroll
      for (int mi2 = 0; mi2 < 4; ++mi2) {
        const short4v pa = *(const short4v*)&Ps[w * 2048 + lm * 128 + ((mi2 * 8 + lq * 2 + 0) ^ lm) * 4];
        const short4v pb = *(const short4v*)&Ps[w * 2048 + lm * 128 + ((mi2 * 8 + lq * 2 + 1) ^ lm) * 4];
        const short8 ap = __builtin_shufflevector(pa, pb, 0, 1, 2, 3, 4, 5, 6, 7);
#pragma unroll
        for (int hi = 0; hi < 8; ++hi) {
          const short8 bv = *(const short8*)&Vb[(hi * 16 + lm) * 128 + ((mi2 * 4 + lq) ^ lm) * 8];
          acc[hi] = __builtin_amdgcn_mfma_f32_16x16x32_bf16(ap, bv, acc[hi], 0, 0, 0);
        }
      }
    }
    // epilogue: 1/l, sigmoid gate, store (q = qtb + w*16 + lq*4 + r, h = hi*16+lm)
    const float linv = 1.0f / lsum;
    float lP[4];
#pragma unroll
    for (int r = 0; r < 4; ++r) lP[r] = __shfl(linv, lq * 4 + r);
#pragma unroll
    for (int hi = 0; hi < 8; ++hi)
#pragma unroll
      for (int r = 0; r < 4; ++r) {
        const int t = qtb + w * 16 + lq * 4 + r;
        const int h = hi * 16 + lm;
        const float g = bf2f(qgb[((size_t)t * NH_ + n) * 256 + 128 + h]);
        const float o = acc[hi][r] * lP[r] * (1.0f / (1.0f + __expf(-g)));
        encb[((size_t)t * NH_ + n) * 128 + h] = f2bf(o);
      }
  }
}

// ---------------------------------------------------------------------------
extern "C" void kernel_launch(void* const* d_in, const int* in_sizes, int n_in,
                              void* d_out, int out_size, void* d_ws, size_t ws_size,
                              hipStream_t stream)
{
  (void)in_sizes; (void)n_in; (void)out_size; (void)ws_size;
  const float* x0    = (const float*)d_in[0];
  const float* x1    = (const float*)d_in[1];
  const int*   pos   = (const int*)d_in[2];
  const float* qg_w0 = (const float*)d_in[4];
  const float* k_w0  = (const float*)d_in[5];
  const float* v_w0  = (const float*)d_in[6];
  const float* qn0   = (const float*)d_in[7];
  const float* kn0   = (const float*)d_in[8];
  const float* o_w0  = (const float*)d_in[9];
  const float* qg_w1 = (const float*)d_in[10];
  const float* k_w1  = (const float*)d_in[11];
  const float* v_w1  = (const float*)d_in[12];
  const float* qn1   = (const float*)d_in[13];
  const float* kn1   = (const float*)d_in[14];
  const float* o_w1  = (const float*)d_in[15];

  float* out    = (float*)d_out;
  float* kcache = out + (size_t)TT_ * WD_;
  float* vcache = kcache + (size_t)TT_ * KH_ * 128;
  ushort* qsc = (ushort*)d_out;  // out0/out1 region doubles as qg_w0^T scratch

  // ws: wbuf 16M | xb 8M (-> Kb 2M + Vt 2M after projections) | qgb 16M | encb 8M
  ushort* wbuf = (ushort*)d_ws;
  ushort* xb   = wbuf + 8388608;
  ushort* qgb  = xb + 4194304;
  ushort* encb = qgb + 8388608;
  ushort* Kbuf = xb;
  ushort* Vtb  = xb + 1048576;
  ushort* k0t = encb, *k1t = encb + 1048576, *v0t = encb + 2097152, *v1t = encb + 3145728;

  convert_x<<<4096, 256, 0, stream>>>(x0, x1, xb);

  // weight transposes
  convtrans2<<<dim3(64, 8, 32), 256, 0, stream>>>(qg_w0, qg_w1, qsc, wbuf, WD_, 256, 16);
  convtrans2<<<dim3(64, 4, 8), 256, 0, stream>>>(k_w0, k_w1, k0t, k1t, WD_, 128, 4);
  convtrans2<<<dim3(64, 4, 8), 256, 0, stream>>>(v_w0, v_w1, v0t, v1t, WD_, 128, 4);

  // all projections, one launch
  gemm_proj<<<dim3(40, 16), 256, 0, stream>>>(xb, qsc, wbuf, k0t, k1t, v0t, v1t,
                                              qgb, kcache, vcache);

  // norm + rope (kcache in place -> cached_k; Kb bf16 into xb alias)
  postproc<<<2048, 256, 0, stream>>>(qgb, kcache, Kbuf, pos, qn0, kn0, qn1, kn1);
  // Vt (kh*128+h, t) bf16 from vcache
  convtrans<<<dim3(64, 16, 1), 256, 0, stream>>>(vcache, Vtb, TT_, 512);

  attn<<<dim3(16, 16), 256, 0, stream>>>(qgb, Kbuf, Vtb, encb);

  // output projection
  convtrans2<<<dim3(64, 64, 2), 256, 0, stream>>>(o_w0, o_w1, wbuf, wbuf + 4194304, WD_, WD_, 1);
  gemm_out<<<dim3(16, 16), 256, 0, stream>>>(encb, wbuf, wbuf + 4194304, out);
}

// Round 4
// 374.006 us; speedup vs baseline: 1.0880x; 1.0880x over previous
//
#include <hip/hip_runtime.h>
#include <hip/hip_bf16.h>
#include <cstdint>
#include <cstddef>

#define T0_ 512
#define TT_ 2048
#define WD_ 2048
#define NH_ 16
#define KH_ 4

typedef __attribute__((ext_vector_type(8))) short short8;
typedef __attribute__((ext_vector_type(4))) short short4v;
typedef __attribute__((ext_vector_type(4))) float f32x4;

#define AS1 __attribute__((address_space(1)))
#define AS3 __attribute__((address_space(3)))

__device__ __forceinline__ ushort f2bf(float x) {
  __hip_bfloat16 h = __float2bfloat16(x);
  ushort u; __builtin_memcpy(&u, &h, 2); return u;
}
__device__ __forceinline__ float bf2f(ushort u) {
  __hip_bfloat16 h; __builtin_memcpy(&h, &u, 2);
  return __bfloat162float(h);
}
__device__ __forceinline__ void g2l16(const ushort* g, AS3 ushort* s) {
  __builtin_amdgcn_global_load_lds((const AS1 uint32_t*)g, (AS3 uint32_t*)s, 16, 0, 0);
}

// ---------------------------------------------------------------------------
// x0/x1 (f32) -> xb (2048x2048 bf16)
__global__ __launch_bounds__(256) void convert_x(
    const float* __restrict__ x0, const float* __restrict__ x1, ushort* __restrict__ xb)
{
  const int i = blockIdx.x * 256 + threadIdx.x;
  const int e = i * 4;
  const int row = e >> 11, col = e & 2047;
  const float* src = (row < T0_) ? (x0 + (size_t)row * WD_ + col)
                                 : (x1 + (size_t)(row - T0_) * WD_ + col);
  const float4 v = *(const float4*)src;
  ushort4 o; o.x = f2bf(v.x); o.y = f2bf(v.y); o.z = f2bf(v.z); o.w = f2bf(v.w);
  *(ushort4*)(xb + e) = o;
}

// ---------------------------------------------------------------------------
// Dual-source transpose-convert: z < half -> s0/d0 slab z, else s1/d1 slab z-half.
__global__ __launch_bounds__(256) void convtrans2(
    const float* __restrict__ s0, const float* __restrict__ s1,
    ushort* __restrict__ d0, ushort* __restrict__ d1, int R, int C, int half)
{
  __shared__ float tile[32][33];
  int z = blockIdx.z;
  const float* in; ushort* out;
  if (z < half) { in = s0 + (size_t)z * R * C; out = d0 + (size_t)z * R * C; }
  else { z -= half; in = s1 + (size_t)z * R * C; out = d1 + (size_t)z * R * C; }
  const int r0 = blockIdx.x * 32, c0 = blockIdx.y * 32;
  const int tx = threadIdx.x & 31, ty = threadIdx.x >> 5;
#pragma unroll
  for (int i = 0; i < 4; ++i)
    tile[ty + 8 * i][tx] = in[(size_t)(r0 + ty + 8 * i) * C + c0 + tx];
  __syncthreads();
#pragma unroll
  for (int i = 0; i < 4; ++i)
    out[(size_t)(c0 + ty + 8 * i) * R + r0 + tx] = f2bf(tile[tx][ty + 8 * i]);
}

// ---------------------------------------------------------------------------
// Shared MFMA GEMM core (ROUND-2 PROVEN VERSION): 128x128 C tile, BK=64,
// double-buffered LDS (64 KiB -> 2 blocks/CU co-residency), issue-early stage,
// one __syncthreads per K-step. Chunk-XOR swizzle (conflicts measured 0):
// write side pre-swizzles the GLOBAL chunk, read side slot = chunk ^ (lm&7).
__device__ __forceinline__ void gemm_core(
    const ushort* __restrict__ A, const ushort* __restrict__ Bt,
    int row0, int col0, ushort* As, ushort* Bs, f32x4 (&acc)[4][4])
{
  const int tid = threadIdx.x;
  const int w = tid >> 6, l = tid & 63, lq = l >> 4, lm = l & 15;
  const int wr = (w >> 1) * 64, wc = (w & 1) * 64;
  const int sx = lm & 7;                               // read-swizzle key
  const int gsw = (tid & 7) ^ ((tid >> 3) & 7);        // pre-swizzled source chunk
  const ushort* Ag = A + (size_t)(row0 + (tid >> 3)) * WD_ + gsw * 8;
  const ushort* Bg = Bt + (size_t)(col0 + (tid >> 3)) * WD_ + gsw * 8;
  AS3 ushort* AsW = (AS3 ushort*)As + w * 512;   // wave w: rows w*8 + c*32
  AS3 ushort* BsW = (AS3 ushort*)Bs + w * 512;

  auto stage = [&](int buf, int k0) {
#pragma unroll
    for (int c = 0; c < 4; ++c) {
      g2l16(Ag + (size_t)(c * 32) * WD_ + k0, AsW + buf * 8192 + c * 2048);
      g2l16(Bg + (size_t)(c * 32) * WD_ + k0, BsW + buf * 8192 + c * 2048);
    }
  };

  stage(0, 0);
  __syncthreads();           // prologue: tile 0 resident
  int buf = 0;
  for (int k0 = 0; k0 < WD_; k0 += 64) {
    if (k0 + 64 < WD_) stage(buf ^ 1, k0 + 64);   // issue early, fly under compute
    const ushort* Ab = As + buf * 8192;
    const ushort* Bb = Bs + buf * 8192;
#pragma unroll
    for (int kk = 0; kk < 2; ++kk) {
      short8 af[4], bfr[4];
#pragma unroll
      for (int mi = 0; mi < 4; ++mi)
        af[mi] = *(const short8*)&Ab[(wr + mi * 16 + lm) * 64 + (((kk * 4 + lq) ^ sx) << 3)];
#pragma unroll
      for (int ni = 0; ni < 4; ++ni)
        bfr[ni] = *(const short8*)&Bb[(wc + ni * 16 + lm) * 64 + (((kk * 4 + lq) ^ sx) << 3)];
#pragma unroll
      for (int mi = 0; mi < 4; ++mi)
#pragma unroll
        for (int ni = 0; ni < 4; ++ni)
          acc[mi][ni] = __builtin_amdgcn_mfma_f32_16x16x32_bf16(af[mi], bfr[ni], acc[mi][ni], 0, 0, 0);
    }
    __syncthreads();         // drains vmcnt(0)+lgkmcnt(0): next buf ready, reads done
    buf ^= 1;
  }
}

// ---------------------------------------------------------------------------
// All projections in one launch. grid (40, 16):
//  bx<32: qg (bf16, ldc 4096) | bx 32..35: k->kcache f32 | bx 36..39: v->vcache f32
__global__ __launch_bounds__(256) void gemm_proj(
    const ushort* __restrict__ A,
    const ushort* __restrict__ qg0t, const ushort* __restrict__ qg1t,
    const ushort* __restrict__ k0t,  const ushort* __restrict__ k1t,
    const ushort* __restrict__ v0t,  const ushort* __restrict__ v1t,
    ushort* __restrict__ Cqg, float* __restrict__ kc, float* __restrict__ vc)
{
  __shared__ ushort As[16384], Bs[16384];
  const int bx = blockIdx.x;
  const int row0 = blockIdx.y * 128;
  const bool s1 = (row0 >= T0_);
  const ushort* Bt; int col0;
  float* Cf = nullptr; ushort* Cb = nullptr; int ldc;
  if (bx < 32) {
    Bt = s1 ? qg1t : qg0t; col0 = bx * 128; Cb = Cqg; ldc = 4096;
  } else if (bx < 36) {
    Bt = s1 ? k1t : k0t; col0 = (bx - 32) * 128; Cf = kc; ldc = 512;
  } else {
    Bt = s1 ? v1t : v0t; col0 = (bx - 36) * 128; Cf = vc; ldc = 512;
  }
  f32x4 acc[4][4];
#pragma unroll
  for (int mi = 0; mi < 4; ++mi)
#pragma unroll
    for (int ni = 0; ni < 4; ++ni) acc[mi][ni] = (f32x4){0.f, 0.f, 0.f, 0.f};
  gemm_core(A, Bt, row0, col0, As, Bs, acc);
  const int w = threadIdx.x >> 6, l = threadIdx.x & 63, lq = l >> 4, lm = l & 15;
  const int wr = (w >> 1) * 64, wc = (w & 1) * 64;
#pragma unroll
  for (int mi = 0; mi < 4; ++mi)
#pragma unroll
    for (int ni = 0; ni < 4; ++ni)
#pragma unroll
      for (int r = 0; r < 4; ++r) {
        const size_t rr = (size_t)row0 + wr + mi * 16 + lq * 4 + r;
        const size_t cc = (size_t)col0 + wc + ni * 16 + lm;
        if (Cb) Cb[rr * ldc + cc] = f2bf(acc[mi][ni][r]);
        else    Cf[rr * ldc + cc] = acc[mi][ni][r];
      }
}

// out projection: grid (16, 16); C f32 (t, 2048), weight by stream.
__global__ __launch_bounds__(256) void gemm_out(
    const ushort* __restrict__ A, const ushort* __restrict__ W0t,
    const ushort* __restrict__ W1t, float* __restrict__ C)
{
  __shared__ ushort As[16384], Bs[16384];
  const int row0 = blockIdx.y * 128, col0 = blockIdx.x * 128;
  const ushort* Bt = (row0 < T0_) ? W0t : W1t;
  f32x4 acc[4][4];
#pragma unroll
  for (int mi = 0; mi < 4; ++mi)
#pragma unroll
    for (int ni = 0; ni < 4; ++ni) acc[mi][ni] = (f32x4){0.f, 0.f, 0.f, 0.f};
  gemm_core(A, Bt, row0, col0, As, Bs, acc);
  const int w = threadIdx.x >> 6, l = threadIdx.x & 63, lq = l >> 4, lm = l & 15;
  const int wr = (w >> 1) * 64, wc = (w & 1) * 64;
#pragma unroll
  for (int mi = 0; mi < 4; ++mi)
#pragma unroll
    for (int ni = 0; ni < 4; ++ni)
#pragma unroll
      for (int r = 0; r < 4; ++r) {
        const size_t rr = (size_t)row0 + wr + mi * 16 + lq * 4 + r;
        const size_t cc = (size_t)col0 + wc + ni * 16 + lm;
        C[rr * 2048 + cc] = acc[mi][ni][r];
      }
}

// ---------------------------------------------------------------------------
// Fused: RMSNorm + RoPE (+ q scale)  [blocks 0..2047]
//        V transpose-convert vcache f32 (2048,512) -> Vtb bf16 (512,2048) [blocks 2048..3071]
__global__ __launch_bounds__(256) void postproc_vt(
    ushort* __restrict__ qgb, float* __restrict__ kc, ushort* __restrict__ Kb,
    const int* __restrict__ positions,
    const float* __restrict__ qn0, const float* __restrict__ kn0,
    const float* __restrict__ qn1, const float* __restrict__ kn1,
    const float* __restrict__ vcache, ushort* __restrict__ Vtb)
{
  __shared__ float tile[32][33];
  if (blockIdx.x >= 2048) {
    const int idx = blockIdx.x - 2048;
    const int r0 = (idx & 63) * 32, c0 = (idx >> 6) * 32;   // R=2048 rows, C=512 cols
    const int tx = threadIdx.x & 31, ty = threadIdx.x >> 5;
#pragma unroll
    for (int i = 0; i < 4; ++i)
      tile[ty + 8 * i][tx] = vcache[(size_t)(r0 + ty + 8 * i) * 512 + c0 + tx];
    __syncthreads();
#pragma unroll
    for (int i = 0; i < 4; ++i)
      Vtb[(size_t)(c0 + ty + 8 * i) * 2048 + r0 + tx] = f2bf(tile[tx][ty + 8 * i]);
    return;
  }
  const int t = blockIdx.x;
  const int w = threadIdx.x >> 6, l = threadIdx.x & 63;
  const float pos = (float)positions[t];
  const bool str1 = (t >= T0_);
  const float* qn = str1 ? qn1 : qn0;
  const float* kn = str1 ? kn1 : kn0;
  const float kfreq = 13.815510557964274f / 32.0f;  // ln(1e6)/32
  const int h0 = 2 * l, h1 = 2 * l + 1;

  for (int r = w; r < NH_ + KH_; r += 4) {
    const bool isq = (r < NH_);
    float v0, v1; size_t bi; const float* sc;
    if (isq) {
      bi = ((size_t)t * NH_ + r) * 256;
      v0 = bf2f(qgb[bi + h0]); v1 = bf2f(qgb[bi + h1]); sc = qn;
    } else {
      bi = ((size_t)t * KH_ + (r - NH_)) * 128;
      v0 = kc[bi + h0]; v1 = kc[bi + h1]; sc = kn;
    }
    float ss = v0 * v0 + v1 * v1;
#pragma unroll
    for (int off = 32; off > 0; off >>= 1) ss += __shfl_xor(ss, off);
    const float rstd = rsqrtf(ss * (1.0f / 128.0f) + 1e-6f);
    v0 = v0 * rstd * (1.0f + sc[h0]);
    v1 = v1 * rstd * (1.0f + sc[h1]);
    const float p0 = __shfl_xor(v0, 16);
    const float p1 = __shfl_xor(v1, 16);
    if (l < 32) {
      const int i0 = (l < 16) ? h0 : (h0 - 32);
      const float a0 = pos * __expf(-(float)i0 * kfreq);
      const float a1 = pos * __expf(-(float)(i0 + 1) * kfreq);
      const float c0 = cosf(a0), s0 = sinf(a0);
      const float c1 = cosf(a1), s1v = sinf(a1);
      if (l < 16) { v0 = v0 * c0 - p0 * s0; v1 = v1 * c1 - p1 * s1v; }
      else        { v0 = v0 * c0 + p0 * s0; v1 = v1 * c1 + p1 * s1v; }
    }
    if (isq) {
      v0 *= 0.08838834764831843f; v1 *= 0.08838834764831843f;
      qgb[bi + h0] = f2bf(v0); qgb[bi + h1] = f2bf(v1);
    } else {
      kc[bi + h0] = v0; kc[bi + h1] = v1;
      Kb[bi + h0] = f2bf(v0); Kb[bi + h1] = f2bf(v1);
    }
  }
}

// ---------------------------------------------------------------------------
// Flash attention, S^T formulation, XOR-swizzled LDS. SB=64 s-step ->
// LDS 72 KiB -> 2 blocks/CU. Grid (32, 16): one qt tile per block,
// qt = (n<8) ? bx : 31-bx so co-scheduled block pairs sum to ~equal work.
// qgb: normed q + raw gate bf16 (t,n,256); Kb (t,kh,128); Vt (kh,128,2048).
__global__ __launch_bounds__(256) void attn(
    const ushort* __restrict__ qgb, const ushort* __restrict__ Kb,
    const ushort* __restrict__ Vt, ushort* __restrict__ encb)
{
  __shared__ ushort Ks[2 * 8192];  // [buf][s 0..63][h 0..127], 16B chunks ^ (s&15)
  __shared__ ushort Vs[2 * 8192];  // [buf][h 0..127][s 0..63],  16B chunks ^ (h&7)
  __shared__ ushort Ps[4 * 1024];  // per-wave [q 0..15][s 0..63], 8B units ^ lm
  const int tid = threadIdx.x;
  const int w = tid >> 6, l = tid & 63, lq = l >> 4, lm = l & 15;
  const int n = blockIdx.y, kh = n >> 2;
  const int qt = (n < 8) ? (int)blockIdx.x : (31 - (int)blockIdx.x);
  const int qtb = qt * 64;
  const int nst = qt + 1;          // 64-wide s-steps

  // stage one 64x128 K tile (4 rows/instr) + 128x64 V tile (8 rows/instr)
  auto stage = [&](int buf, int s0) {
#pragma unroll
    for (int c = 0; c < 4; ++c) {
      {
        const int base = c * 16 + w * 4;          // K s-row base
        const int row = base + (l >> 4);
        const int j = l & 15;
        g2l16(Kb + (size_t)(s0 + row) * 512 + kh * 128 + (j ^ (row & 15)) * 8,
              (AS3 ushort*)Ks + buf * 8192 + base * 128);
      }
      {
        const int base = c * 32 + w * 8;          // V h-row base
        const int row = base + (l >> 3);
        const int j = l & 7;
        g2l16(Vt + (size_t)(kh * 128 + row) * 2048 + s0 + (j ^ (row & 7)) * 8,
              (AS3 ushort*)Vs + buf * 8192 + base * 64);
      }
    }
  };

  short8 aq[4];
  {
    const ushort* qb = qgb + ((size_t)(qtb + w * 16 + lm) * NH_ + n) * 256 + lq * 8;
#pragma unroll
    for (int kk = 0; kk < 4; ++kk) aq[kk] = *(const short8*)(qb + kk * 32);
  }
  f32x4 acc[8];
#pragma unroll
  for (int i = 0; i < 8; ++i) acc[i] = (f32x4){0.f, 0.f, 0.f, 0.f};
  float mq = -3.0e38f, lsum = 0.0f;  // softmax state for q = qtb + w*16 + lm

  stage(0, 0);

  for (int st = 0; st < nst; ++st) {
    const int buf = st & 1;
    const int s0 = st * 64;
    __syncthreads();  // stage(st) visible; prev-iter LDS reads complete
    if (st + 1 < nst) stage(buf ^ 1, s0 + 64);
    const ushort* Kt = Ks + buf * 8192;
    const ushort* Vb = Vs + buf * 8192;

    // S^T = K * Q^T : D[m=s][n=q]
    f32x4 sa[4];
#pragma unroll
    for (int mi = 0; mi < 4; ++mi) sa[mi] = (f32x4){0.f, 0.f, 0.f, 0.f};
#pragma unroll
    for (int kk = 0; kk < 4; ++kk)
#pragma unroll
      for (int mi = 0; mi < 4; ++mi) {
        const short8 ak = *(const short8*)&Kt[(mi * 16 + lm) * 128 + ((kk * 4 + lq) ^ lm) * 8];
        sa[mi] = __builtin_amdgcn_mfma_f32_16x16x32_bf16(ak, aq[kk], sa[mi], 0, 0, 0);
      }
    // causal mask: s > q -> -inf (only possible in the last step, s0 == qtb)
    if (s0 + 63 > qtb) {
      const int qg_ = qtb + w * 16 + lm;
#pragma unroll
      for (int mi = 0; mi < 4; ++mi)
#pragma unroll
        for (int r = 0; r < 4; ++r)
          if (s0 + mi * 16 + lq * 4 + r > qg_) sa[mi][r] = -3.0e38f;
    }
    // online softmax over s (in-lane 16 vals + 2 shfl levels)
    float mx = sa[0][0];
#pragma unroll
    for (int mi = 0; mi < 4; ++mi)
#pragma unroll
      for (int r = 0; r < 4; ++r) mx = fmaxf(mx, sa[mi][r]);
    mx = fmaxf(mx, __shfl_xor(mx, 16));
    mx = fmaxf(mx, __shfl_xor(mx, 32));
    const float mn = fmaxf(mq, mx);
    const float alpha = __expf(mq - mn);
    mq = mn;
    float sl = 0.0f;
#pragma unroll
    for (int mi = 0; mi < 4; ++mi)
#pragma unroll
      for (int r = 0; r < 4; ++r) {
        const float p = __expf(sa[mi][r] - mn);
        sa[mi][r] = p; sl += p;
      }
    sl += __shfl_xor(sl, 16);
    sl += __shfl_xor(sl, 32);
    lsum = lsum * alpha + sl;

    // P -> per-wave LDS [q][s], bf16, 4-short units, unit index (s/4) ^ lm
#pragma unroll
    for (int mi = 0; mi < 4; ++mi) {
      short4v pw;
#pragma unroll
      for (int r = 0; r < 4; ++r) pw[r] = (short)f2bf(sa[mi][r]);
      *(short4v*)&Ps[w * 1024 + lm * 64 + ((mi * 4 + lq) ^ lm) * 4] = pw;
    }
    // rescale acc (alpha for q = lq*4+r lives in lane lq*4+r)
    float aP[4];
#pragma unroll
    for (int r = 0; r < 4; ++r) aP[r] = __shfl(alpha, lq * 4 + r);
#pragma unroll
    for (int hi = 0; hi < 8; ++hi) {
      f32x4 a = acc[hi];
#pragma unroll
      for (int r = 0; r < 4; ++r) a[r] *= aP[r];
      acc[hi] = a;
    }
    // O += P V : A = P[q][s] from Ps (k-chunk mi2 in {0,1}: s/4 units
    // mi2*8 + lq*2 + {0,1}), B = V[s][h] from Vs (s/8 unit (mi2*4+lq) ^ (lm&7))
#pragma unroll
    for (int mi2 = 0; mi2 < 2; ++mi2) {
      const short4v pa = *(const short4v*)&Ps[w * 1024 + lm * 64 + ((mi2 * 8 + lq * 2 + 0) ^ lm) * 4];
      const short4v pb = *(const short4v*)&Ps[w * 1024 + lm * 64 + ((mi2 * 8 + lq * 2 + 1) ^ lm) * 4];
      const short8 ap = __builtin_shufflevector(pa, pb, 0, 1, 2, 3, 4, 5, 6, 7);
#pragma unroll
      for (int hi = 0; hi < 8; ++hi) {
        const short8 bv = *(const short8*)&Vb[(hi * 16 + lm) * 64 + (((mi2 * 4 + lq) ^ (lm & 7)) << 3)];
        acc[hi] = __builtin_amdgcn_mfma_f32_16x16x32_bf16(ap, bv, acc[hi], 0, 0, 0);
      }
    }
  }
  // epilogue: 1/l, sigmoid gate, store (q = qtb + w*16 + lq*4 + r, h = hi*16+lm)
  const float linv = 1.0f / lsum;
  float lP[4];
#pragma unroll
  for (int r = 0; r < 4; ++r) lP[r] = __shfl(linv, lq * 4 + r);
#pragma unroll
  for (int hi = 0; hi < 8; ++hi)
#pragma unroll
    for (int r = 0; r < 4; ++r) {
      const int t = qtb + w * 16 + lq * 4 + r;
      const int h = hi * 16 + lm;
      const float g = bf2f(qgb[((size_t)t * NH_ + n) * 256 + 128 + h]);
      const float o = acc[hi][r] * lP[r] * (1.0f / (1.0f + __expf(-g)));
      encb[((size_t)t * NH_ + n) * 128 + h] = f2bf(o);
    }
}

// ---------------------------------------------------------------------------
extern "C" void kernel_launch(void* const* d_in, const int* in_sizes, int n_in,
                              void* d_out, int out_size, void* d_ws, size_t ws_size,
                              hipStream_t stream)
{
  (void)in_sizes; (void)n_in; (void)out_size; (void)ws_size;
  const float* x0    = (const float*)d_in[0];
  const float* x1    = (const float*)d_in[1];
  const int*   pos   = (const int*)d_in[2];
  const float* qg_w0 = (const float*)d_in[4];
  const float* k_w0  = (const float*)d_in[5];
  const float* v_w0  = (const float*)d_in[6];
  const float* qn0   = (const float*)d_in[7];
  const float* kn0   = (const float*)d_in[8];
  const float* o_w0  = (const float*)d_in[9];
  const float* qg_w1 = (const float*)d_in[10];
  const float* k_w1  = (const float*)d_in[11];
  const float* v_w1  = (const float*)d_in[12];
  const float* qn1   = (const float*)d_in[13];
  const float* kn1   = (const float*)d_in[14];
  const float* o_w1  = (const float*)d_in[15];

  float* out    = (float*)d_out;
  float* kcache = out + (size_t)TT_ * WD_;
  float* vcache = kcache + (size_t)TT_ * KH_ * 128;
  ushort* qsc = (ushort*)d_out;  // out0/out1 region doubles as qg_w0^T scratch

  // ws: wbuf 16M | xb 8M (-> Kb 2M + Vt 2M after projections) | qgb 16M | encb 8M
  ushort* wbuf = (ushort*)d_ws;
  ushort* xb   = wbuf + 8388608;
  ushort* qgb  = xb + 4194304;
  ushort* encb = qgb + 8388608;
  ushort* Kbuf = xb;
  ushort* Vtb  = xb + 1048576;
  ushort* k0t = encb, *k1t = encb + 1048576, *v0t = encb + 2097152, *v1t = encb + 3145728;

  convert_x<<<4096, 256, 0, stream>>>(x0, x1, xb);

  // weight transposes
  convtrans2<<<dim3(64, 8, 32), 256, 0, stream>>>(qg_w0, qg_w1, qsc, wbuf, WD_, 256, 16);
  convtrans2<<<dim3(64, 4, 8), 256, 0, stream>>>(k_w0, k_w1, k0t, k1t, WD_, 128, 4);
  convtrans2<<<dim3(64, 4, 8), 256, 0, stream>>>(v_w0, v_w1, v0t, v1t, WD_, 128, 4);

  // all projections, one launch
  gemm_proj<<<dim3(40, 16), 256, 0, stream>>>(xb, qsc, wbuf, k0t, k1t, v0t, v1t,
                                              qgb, kcache, vcache);

  // norm + rope (kcache in place -> cached_k; Kb bf16 into xb alias)
  // + fused V transpose: Vt (kh*128+h, t) bf16 from vcache
  postproc_vt<<<3072, 256, 0, stream>>>(qgb, kcache, Kbuf, pos, qn0, kn0, qn1, kn1,
                                        vcache, Vtb);

  attn<<<dim3(32, 16), 256, 0, stream>>>(qgb, Kbuf, Vtb, encb);

  // output projection
  convtrans2<<<dim3(64, 64, 2), 256, 0, stream>>>(o_w0, o_w1, wbuf, wbuf + 4194304, WD_, WD_, 1);
  gemm_out<<<dim3(16, 16), 256, 0, stream>>>(encb, wbuf, wbuf + 4194304, out);
}

// Round 5
// 373.806 us; speedup vs baseline: 1.0886x; 1.0005x over previous
//
#include <hip/hip_runtime.h>
#include <hip/hip_bf16.h>
#include <cstdint>
#include <cstddef>

#define T0_ 512
#define TT_ 2048
#define WD_ 2048
#define NH_ 16
#define KH_ 4

typedef __attribute__((ext_vector_type(8))) short short8;
typedef __attribute__((ext_vector_type(4))) short short4v;
typedef __attribute__((ext_vector_type(4))) float f32x4;

#define AS1 __attribute__((address_space(1)))
#define AS3 __attribute__((address_space(3)))

__device__ __forceinline__ ushort f2bf(float x) {
  __hip_bfloat16 h = __float2bfloat16(x);
  ushort u; __builtin_memcpy(&u, &h, 2); return u;
}
__device__ __forceinline__ float bf2f(ushort u) {
  __hip_bfloat16 h; __builtin_memcpy(&h, &u, 2);
  return __bfloat162float(h);
}
__device__ __forceinline__ void g2l16(const ushort* g, AS3 ushort* s) {
  __builtin_amdgcn_global_load_lds((const AS1 uint32_t*)g, (AS3 uint32_t*)s, 16, 0, 0);
}

// ---------------------------------------------------------------------------
// x0/x1 (f32) -> xb (2048x2048 bf16)
__global__ __launch_bounds__(256) void convert_x(
    const float* __restrict__ x0, const float* __restrict__ x1, ushort* __restrict__ xb)
{
  const int i = blockIdx.x * 256 + threadIdx.x;
  const int e = i * 4;
  const int row = e >> 11, col = e & 2047;
  const float* src = (row < T0_) ? (x0 + (size_t)row * WD_ + col)
                                 : (x1 + (size_t)(row - T0_) * WD_ + col);
  const float4 v = *(const float4*)src;
  ushort4 o; o.x = f2bf(v.x); o.y = f2bf(v.y); o.z = f2bf(v.z); o.w = f2bf(v.w);
  *(ushort4*)(xb + e) = o;
}

// ---------------------------------------------------------------------------
// Fast 64x64 transpose-convert: in f32 (slab,R,C) -> out bf16 (slab,C,R).
// float4 reads (16B/lane), LDS staged TRANSPOSED (stride 67: both scalar
// write & read sides are 2-way bank aliasing = free), ushort4 stores (8B/lane,
// 128B per 16-lane row). Replaces the old 32x32 version whose 2B scalar
// stores capped it ~1.5 TB/s. Dual-source: z<half -> s0/d0, else s1/d1.
__global__ __launch_bounds__(256) void convtrans64(
    const float* __restrict__ s0, const float* __restrict__ s1,
    ushort* __restrict__ d0, ushort* __restrict__ d1, int R, int C, int half)
{
  __shared__ float tile[64][67];   // tile[c][r] = in[r][c]
  int z = blockIdx.z;
  const float* in; ushort* out;
  if (z < half) { in = s0 + (size_t)z * R * C; out = d0 + (size_t)z * R * C; }
  else { z -= half; in = s1 + (size_t)z * R * C; out = d1 + (size_t)z * R * C; }
  const int r0 = blockIdx.x * 64, c0 = blockIdx.y * 64;
  const int cx = threadIdx.x & 15, ry = threadIdx.x >> 4;
#pragma unroll
  for (int i = 0; i < 4; ++i) {
    const int r = ry + i * 16;
    const float4 v = *(const float4*)&in[(size_t)(r0 + r) * C + c0 + cx * 4];
    tile[cx * 4 + 0][r] = v.x;
    tile[cx * 4 + 1][r] = v.y;
    tile[cx * 4 + 2][r] = v.z;
    tile[cx * 4 + 3][r] = v.w;
  }
  __syncthreads();
  const int rq = threadIdx.x & 15, cy = threadIdx.x >> 4;
#pragma unroll
  for (int i = 0; i < 4; ++i) {
    const int c = cy + i * 16;
    ushort4 o;
    o.x = f2bf(tile[c][rq * 4 + 0]);
    o.y = f2bf(tile[c][rq * 4 + 1]);
    o.z = f2bf(tile[c][rq * 4 + 2]);
    o.w = f2bf(tile[c][rq * 4 + 3]);
    *(ushort4*)&out[(size_t)(c0 + c) * R + r0 + rq * 4] = o;
  }
}

// ---------------------------------------------------------------------------
// Shared MFMA GEMM core (ROUND-2 PROVEN VERSION): 128x128 C tile, BK=64,
// double-buffered LDS (64 KiB -> 2 blocks/CU co-residency), issue-early stage,
// one __syncthreads per K-step. Chunk-XOR swizzle (conflicts measured 0):
// write side pre-swizzles the GLOBAL chunk, read side slot = chunk ^ (lm&7).
__device__ __forceinline__ void gemm_core(
    const ushort* __restrict__ A, const ushort* __restrict__ Bt,
    int row0, int col0, ushort* As, ushort* Bs, f32x4 (&acc)[4][4])
{
  const int tid = threadIdx.x;
  const int w = tid >> 6, l = tid & 63, lq = l >> 4, lm = l & 15;
  const int wr = (w >> 1) * 64, wc = (w & 1) * 64;
  const int sx = lm & 7;                               // read-swizzle key
  const int gsw = (tid & 7) ^ ((tid >> 3) & 7);        // pre-swizzled source chunk
  const ushort* Ag = A + (size_t)(row0 + (tid >> 3)) * WD_ + gsw * 8;
  const ushort* Bg = Bt + (size_t)(col0 + (tid >> 3)) * WD_ + gsw * 8;
  AS3 ushort* AsW = (AS3 ushort*)As + w * 512;   // wave w: rows w*8 + c*32
  AS3 ushort* BsW = (AS3 ushort*)Bs + w * 512;

  auto stage = [&](int buf, int k0) {
#pragma unroll
    for (int c = 0; c < 4; ++c) {
      g2l16(Ag + (size_t)(c * 32) * WD_ + k0, AsW + buf * 8192 + c * 2048);
      g2l16(Bg + (size_t)(c * 32) * WD_ + k0, BsW + buf * 8192 + c * 2048);
    }
  };

  stage(0, 0);
  __syncthreads();           // prologue: tile 0 resident
  int buf = 0;
  for (int k0 = 0; k0 < WD_; k0 += 64) {
    if (k0 + 64 < WD_) stage(buf ^ 1, k0 + 64);   // issue early, fly under compute
    const ushort* Ab = As + buf * 8192;
    const ushort* Bb = Bs + buf * 8192;
#pragma unroll
    for (int kk = 0; kk < 2; ++kk) {
      short8 af[4], bfr[4];
#pragma unroll
      for (int mi = 0; mi < 4; ++mi)
        af[mi] = *(const short8*)&Ab[(wr + mi * 16 + lm) * 64 + (((kk * 4 + lq) ^ sx) << 3)];
#pragma unroll
      for (int ni = 0; ni < 4; ++ni)
        bfr[ni] = *(const short8*)&Bb[(wc + ni * 16 + lm) * 64 + (((kk * 4 + lq) ^ sx) << 3)];
#pragma unroll
      for (int mi = 0; mi < 4; ++mi)
#pragma unroll
        for (int ni = 0; ni < 4; ++ni)
          acc[mi][ni] = __builtin_amdgcn_mfma_f32_16x16x32_bf16(af[mi], bfr[ni], acc[mi][ni], 0, 0, 0);
    }
    __syncthreads();         // drains vmcnt(0)+lgkmcnt(0): next buf ready, reads done
    buf ^= 1;
  }
}

// ---------------------------------------------------------------------------
// All projections in one launch. grid (40, 16):
//  bx<32: qg (bf16, ldc 4096) | bx 32..35: k->kcache f32 | bx 36..39: v->vcache f32
__global__ __launch_bounds__(256) void gemm_proj(
    const ushort* __restrict__ A,
    const ushort* __restrict__ qg0t, const ushort* __restrict__ qg1t,
    const ushort* __restrict__ k0t,  const ushort* __restrict__ k1t,
    const ushort* __restrict__ v0t,  const ushort* __restrict__ v1t,
    ushort* __restrict__ Cqg, float* __restrict__ kc, float* __restrict__ vc)
{
  __shared__ ushort As[16384], Bs[16384];
  const int bx = blockIdx.x;
  const int row0 = blockIdx.y * 128;
  const bool s1 = (row0 >= T0_);
  const ushort* Bt; int col0;
  float* Cf = nullptr; ushort* Cb = nullptr; int ldc;
  if (bx < 32) {
    Bt = s1 ? qg1t : qg0t; col0 = bx * 128; Cb = Cqg; ldc = 4096;
  } else if (bx < 36) {
    Bt = s1 ? k1t : k0t; col0 = (bx - 32) * 128; Cf = kc; ldc = 512;
  } else {
    Bt = s1 ? v1t : v0t; col0 = (bx - 36) * 128; Cf = vc; ldc = 512;
  }
  f32x4 acc[4][4];
#pragma unroll
  for (int mi = 0; mi < 4; ++mi)
#pragma unroll
    for (int ni = 0; ni < 4; ++ni) acc[mi][ni] = (f32x4){0.f, 0.f, 0.f, 0.f};
  gemm_core(A, Bt, row0, col0, As, Bs, acc);
  const int w = threadIdx.x >> 6, l = threadIdx.x & 63, lq = l >> 4, lm = l & 15;
  const int wr = (w >> 1) * 64, wc = (w & 1) * 64;
#pragma unroll
  for (int mi = 0; mi < 4; ++mi)
#pragma unroll
    for (int ni = 0; ni < 4; ++ni)
#pragma unroll
      for (int r = 0; r < 4; ++r) {
        const size_t rr = (size_t)row0 + wr + mi * 16 + lq * 4 + r;
        const size_t cc = (size_t)col0 + wc + ni * 16 + lm;
        if (Cb) Cb[rr * ldc + cc] = f2bf(acc[mi][ni][r]);
        else    Cf[rr * ldc + cc] = acc[mi][ni][r];
      }
}

// out projection: grid (16, 16); C f32 (t, 2048), weight by stream.
__global__ __launch_bounds__(256) void gemm_out(
    const ushort* __restrict__ A, const ushort* __restrict__ W0t,
    const ushort* __restrict__ W1t, float* __restrict__ C)
{
  __shared__ ushort As[16384], Bs[16384];
  const int row0 = blockIdx.y * 128, col0 = blockIdx.x * 128;
  const ushort* Bt = (row0 < T0_) ? W0t : W1t;
  f32x4 acc[4][4];
#pragma unroll
  for (int mi = 0; mi < 4; ++mi)
#pragma unroll
    for (int ni = 0; ni < 4; ++ni) acc[mi][ni] = (f32x4){0.f, 0.f, 0.f, 0.f};
  gemm_core(A, Bt, row0, col0, As, Bs, acc);
  const int w = threadIdx.x >> 6, l = threadIdx.x & 63, lq = l >> 4, lm = l & 15;
  const int wr = (w >> 1) * 64, wc = (w & 1) * 64;
#pragma unroll
  for (int mi = 0; mi < 4; ++mi)
#pragma unroll
    for (int ni = 0; ni < 4; ++ni)
#pragma unroll
      for (int r = 0; r < 4; ++r) {
        const size_t rr = (size_t)row0 + wr + mi * 16 + lq * 4 + r;
        const size_t cc = (size_t)col0 + wc + ni * 16 + lm;
        C[rr * 2048 + cc] = acc[mi][ni][r];
      }
}

// ---------------------------------------------------------------------------
// Fused: RMSNorm + RoPE (+ q scale)  [blocks 0..2047]
//        V transpose vcache f32 (2048,512) -> Vtb bf16 (512,2048), 64x64 tiles
//        [blocks 2048..2303]
__global__ __launch_bounds__(256) void postproc_vt(
    ushort* __restrict__ qgb, float* __restrict__ kc, ushort* __restrict__ Kb,
    const int* __restrict__ positions,
    const float* __restrict__ qn0, const float* __restrict__ kn0,
    const float* __restrict__ qn1, const float* __restrict__ kn1,
    const float* __restrict__ vcache, ushort* __restrict__ Vtb)
{
  __shared__ float tile[64][67];
  if (blockIdx.x >= 2048) {
    const int idx = blockIdx.x - 2048;           // 32 r-tiles x 8 c-tiles
    const int r0 = (idx & 31) * 64, c0 = (idx >> 5) * 64;
    const int cx = threadIdx.x & 15, ry = threadIdx.x >> 4;
#pragma unroll
    for (int i = 0; i < 4; ++i) {
      const int r = ry + i * 16;
      const float4 v = *(const float4*)&vcache[(size_t)(r0 + r) * 512 + c0 + cx * 4];
      tile[cx * 4 + 0][r] = v.x;
      tile[cx * 4 + 1][r] = v.y;
      tile[cx * 4 + 2][r] = v.z;
      tile[cx * 4 + 3][r] = v.w;
    }
    __syncthreads();
    const int rq = threadIdx.x & 15, cy = threadIdx.x >> 4;
#pragma unroll
    for (int i = 0; i < 4; ++i) {
      const int c = cy + i * 16;
      ushort4 o;
      o.x = f2bf(tile[c][rq * 4 + 0]);
      o.y = f2bf(tile[c][rq * 4 + 1]);
      o.z = f2bf(tile[c][rq * 4 + 2]);
      o.w = f2bf(tile[c][rq * 4 + 3]);
      *(ushort4*)&Vtb[(size_t)(c0 + c) * 2048 + r0 + rq * 4] = o;
    }
    return;
  }
  const int t = blockIdx.x;
  const int w = threadIdx.x >> 6, l = threadIdx.x & 63;
  const float pos = (float)positions[t];
  const bool str1 = (t >= T0_);
  const float* qn = str1 ? qn1 : qn0;
  const float* kn = str1 ? kn1 : kn0;
  const float kfreq = 13.815510557964274f / 32.0f;  // ln(1e6)/32
  const int h0 = 2 * l, h1 = 2 * l + 1;

  for (int r = w; r < NH_ + KH_; r += 4) {
    const bool isq = (r < NH_);
    float v0, v1; size_t bi; const float* sc;
    if (isq) {
      bi = ((size_t)t * NH_ + r) * 256;
      v0 = bf2f(qgb[bi + h0]); v1 = bf2f(qgb[bi + h1]); sc = qn;
    } else {
      bi = ((size_t)t * KH_ + (r - NH_)) * 128;
      v0 = kc[bi + h0]; v1 = kc[bi + h1]; sc = kn;
    }
    float ss = v0 * v0 + v1 * v1;
#pragma unroll
    for (int off = 32; off > 0; off >>= 1) ss += __shfl_xor(ss, off);
    const float rstd = rsqrtf(ss * (1.0f / 128.0f) + 1e-6f);
    v0 = v0 * rstd * (1.0f + sc[h0]);
    v1 = v1 * rstd * (1.0f + sc[h1]);
    const float p0 = __shfl_xor(v0, 16);
    const float p1 = __shfl_xor(v1, 16);
    if (l < 32) {
      const int i0 = (l < 16) ? h0 : (h0 - 32);
      const float a0 = pos * __expf(-(float)i0 * kfreq);
      const float a1 = pos * __expf(-(float)(i0 + 1) * kfreq);
      const float c0 = cosf(a0), s0 = sinf(a0);
      const float c1 = cosf(a1), s1v = sinf(a1);
      if (l < 16) { v0 = v0 * c0 - p0 * s0; v1 = v1 * c1 - p1 * s1v; }
      else        { v0 = v0 * c0 + p0 * s0; v1 = v1 * c1 + p1 * s1v; }
    }
    if (isq) {
      v0 *= 0.08838834764831843f; v1 *= 0.08838834764831843f;
      qgb[bi + h0] = f2bf(v0); qgb[bi + h1] = f2bf(v1);
    } else {
      kc[bi + h0] = v0; kc[bi + h1] = v1;
      Kb[bi + h0] = f2bf(v0); Kb[bi + h1] = f2bf(v1);
    }
  }
}

// ---------------------------------------------------------------------------
// Flash attention, S^T formulation, XOR-swizzled LDS. SB=64 s-step ->
// LDS 72 KiB -> 2 blocks/CU. Grid (32, 16): one qt tile per block,
// qt = (n<8) ? bx : 31-bx so co-scheduled block pairs sum to ~equal work.
// qgb: normed q + raw gate bf16 (t,n,256); Kb (t,kh,128); Vt (kh,128,2048).
__global__ __launch_bounds__(256) void attn(
    const ushort* __restrict__ qgb, const ushort* __restrict__ Kb,
    const ushort* __restrict__ Vt, ushort* __restrict__ encb)
{
  __shared__ ushort Ks[2 * 8192];  // [buf][s 0..63][h 0..127], 16B chunks ^ (s&15)
  __shared__ ushort Vs[2 * 8192];  // [buf][h 0..127][s 0..63],  16B chunks ^ (h&7)
  __shared__ ushort Ps[4 * 1024];  // per-wave [q 0..15][s 0..63], 8B units ^ lm
  const int tid = threadIdx.x;
  const int w = tid >> 6, l = tid & 63, lq = l >> 4, lm = l & 15;
  const int n = blockIdx.y, kh = n >> 2;
  const int qt = (n < 8) ? (int)blockIdx.x : (31 - (int)blockIdx.x);
  const int qtb = qt * 64;
  const int nst = qt + 1;          // 64-wide s-steps

  // stage one 64x128 K tile (4 rows/instr) + 128x64 V tile (8 rows/instr)
  auto stage = [&](int buf, int s0) {
#pragma unroll
    for (int c = 0; c < 4; ++c) {
      {
        const int base = c * 16 + w * 4;          // K s-row base
        const int row = base + (l >> 4);
        const int j = l & 15;
        g2l16(Kb + (size_t)(s0 + row) * 512 + kh * 128 + (j ^ (row & 15)) * 8,
              (AS3 ushort*)Ks + buf * 8192 + base * 128);
      }
      {
        const int base = c * 32 + w * 8;          // V h-row base
        const int row = base + (l >> 3);
        const int j = l & 7;
        g2l16(Vt + (size_t)(kh * 128 + row) * 2048 + s0 + (j ^ (row & 7)) * 8,
              (AS3 ushort*)Vs + buf * 8192 + base * 64);
      }
    }
  };

  short8 aq[4];
  {
    const ushort* qb = qgb + ((size_t)(qtb + w * 16 + lm) * NH_ + n) * 256 + lq * 8;
#pragma unroll
    for (int kk = 0; kk < 4; ++kk) aq[kk] = *(const short8*)(qb + kk * 32);
  }
  f32x4 acc[8];
#pragma unroll
  for (int i = 0; i < 8; ++i) acc[i] = (f32x4){0.f, 0.f, 0.f, 0.f};
  float mq = -3.0e38f, lsum = 0.0f;  // softmax state for q = qtb + w*16 + lm

  stage(0, 0);

  for (int st = 0; st < nst; ++st) {
    const int buf = st & 1;
    const int s0 = st * 64;
    __syncthreads();  // stage(st) visible; prev-iter LDS reads complete
    if (st + 1 < nst) stage(buf ^ 1, s0 + 64);
    const ushort* Kt = Ks + buf * 8192;
    const ushort* Vb = Vs + buf * 8192;

    // S^T = K * Q^T : D[m=s][n=q]
    f32x4 sa[4];
#pragma unroll
    for (int mi = 0; mi < 4; ++mi) sa[mi] = (f32x4){0.f, 0.f, 0.f, 0.f};
#pragma unroll
    for (int kk = 0; kk < 4; ++kk)
#pragma unroll
      for (int mi = 0; mi < 4; ++mi) {
        const short8 ak = *(const short8*)&Kt[(mi * 16 + lm) * 128 + ((kk * 4 + lq) ^ lm) * 8];
        sa[mi] = __builtin_amdgcn_mfma_f32_16x16x32_bf16(ak, aq[kk], sa[mi], 0, 0, 0);
      }
    // causal mask: s > q -> -inf (only possible in the last step, s0 == qtb)
    if (s0 + 63 > qtb) {
      const int qg_ = qtb + w * 16 + lm;
#pragma unroll
      for (int mi = 0; mi < 4; ++mi)
#pragma unroll
        for (int r = 0; r < 4; ++r)
          if (s0 + mi * 16 + lq * 4 + r > qg_) sa[mi][r] = -3.0e38f;
    }
    // online softmax over s (in-lane 16 vals + 2 shfl levels)
    float mx = sa[0][0];
#pragma unroll
    for (int mi = 0; mi < 4; ++mi)
#pragma unroll
      for (int r = 0; r < 4; ++r) mx = fmaxf(mx, sa[mi][r]);
    mx = fmaxf(mx, __shfl_xor(mx, 16));
    mx = fmaxf(mx, __shfl_xor(mx, 32));
    const float mn = fmaxf(mq, mx);
    const float alpha = __expf(mq - mn);
    mq = mn;
    float sl = 0.0f;
#pragma unroll
    for (int mi = 0; mi < 4; ++mi)
#pragma unroll
      for (int r = 0; r < 4; ++r) {
        const float p = __expf(sa[mi][r] - mn);
        sa[mi][r] = p; sl += p;
      }
    sl += __shfl_xor(sl, 16);
    sl += __shfl_xor(sl, 32);
    lsum = lsum * alpha + sl;

    // P -> per-wave LDS [q][s], bf16, 4-short units, unit index (s/4) ^ lm
#pragma unroll
    for (int mi = 0; mi < 4; ++mi) {
      short4v pw;
#pragma unroll
      for (int r = 0; r < 4; ++r) pw[r] = (short)f2bf(sa[mi][r]);
      *(short4v*)&Ps[w * 1024 + lm * 64 + ((mi * 4 + lq) ^ lm) * 4] = pw;
    }
    // rescale acc (alpha for q = lq*4+r lives in lane lq*4+r)
    float aP[4];
#pragma unroll
    for (int r = 0; r < 4; ++r) aP[r] = __shfl(alpha, lq * 4 + r);
#pragma unroll
    for (int hi = 0; hi < 8; ++hi) {
      f32x4 a = acc[hi];
#pragma unroll
      for (int r = 0; r < 4; ++r) a[r] *= aP[r];
      acc[hi] = a;
    }
    // O += P V : A = P[q][s] from Ps (k-chunk mi2 in {0,1}: s/4 units
    // mi2*8 + lq*2 + {0,1}), B = V[s][h] from Vs (s/8 unit (mi2*4+lq) ^ (lm&7))
#pragma unroll
    for (int mi2 = 0; mi2 < 2; ++mi2) {
      const short4v pa = *(const short4v*)&Ps[w * 1024 + lm * 64 + ((mi2 * 8 + lq * 2 + 0) ^ lm) * 4];
      const short4v pb = *(const short4v*)&Ps[w * 1024 + lm * 64 + ((mi2 * 8 + lq * 2 + 1) ^ lm) * 4];
      const short8 ap = __builtin_shufflevector(pa, pb, 0, 1, 2, 3, 4, 5, 6, 7);
#pragma unroll
      for (int hi = 0; hi < 8; ++hi) {
        const short8 bv = *(const short8*)&Vb[(hi * 16 + lm) * 64 + (((mi2 * 4 + lq) ^ (lm & 7)) << 3)];
        acc[hi] = __builtin_amdgcn_mfma_f32_16x16x32_bf16(ap, bv, acc[hi], 0, 0, 0);
      }
    }
  }
  // epilogue: 1/l, sigmoid gate, store (q = qtb + w*16 + lq*4 + r, h = hi*16+lm)
  const float linv = 1.0f / lsum;
  float lP[4];
#pragma unroll
  for (int r = 0; r < 4; ++r) lP[r] = __shfl(linv, lq * 4 + r);
#pragma unroll
  for (int hi = 0; hi < 8; ++hi)
#pragma unroll
    for (int r = 0; r < 4; ++r) {
      const int t = qtb + w * 16 + lq * 4 + r;
      const int h = hi * 16 + lm;
      const float g = bf2f(qgb[((size_t)t * NH_ + n) * 256 + 128 + h]);
      const float o = acc[hi][r] * lP[r] * (1.0f / (1.0f + __expf(-g)));
      encb[((size_t)t * NH_ + n) * 128 + h] = f2bf(o);
    }
}

// ---------------------------------------------------------------------------
extern "C" void kernel_launch(void* const* d_in, const int* in_sizes, int n_in,
                              void* d_out, int out_size, void* d_ws, size_t ws_size,
                              hipStream_t stream)
{
  (void)in_sizes; (void)n_in; (void)out_size; (void)ws_size;
  const float* x0    = (const float*)d_in[0];
  const float* x1    = (const float*)d_in[1];
  const int*   pos   = (const int*)d_in[2];
  const float* qg_w0 = (const float*)d_in[4];
  const float* k_w0  = (const float*)d_in[5];
  const float* v_w0  = (const float*)d_in[6];
  const float* qn0   = (const float*)d_in[7];
  const float* kn0   = (const float*)d_in[8];
  const float* o_w0  = (const float*)d_in[9];
  const float* qg_w1 = (const float*)d_in[10];
  const float* k_w1  = (const float*)d_in[11];
  const float* v_w1  = (const float*)d_in[12];
  const float* qn1   = (const float*)d_in[13];
  const float* kn1   = (const float*)d_in[14];
  const float* o_w1  = (const float*)d_in[15];

  float* out    = (float*)d_out;
  float* kcache = out + (size_t)TT_ * WD_;
  float* vcache = kcache + (size_t)TT_ * KH_ * 128;
  ushort* qsc = (ushort*)d_out;  // out0/out1 region doubles as qg_w0^T scratch

  // ws: wbuf 16M | xb 8M (-> Kb 2M + Vt 2M after projections) | qgb 16M | encb 8M
  ushort* wbuf = (ushort*)d_ws;
  ushort* xb   = wbuf + 8388608;
  ushort* qgb  = xb + 4194304;
  ushort* encb = qgb + 8388608;
  ushort* Kbuf = xb;
  ushort* Vtb  = xb + 1048576;
  ushort* k0t = encb, *k1t = encb + 1048576, *v0t = encb + 2097152, *v1t = encb + 3145728;

  convert_x<<<4096, 256, 0, stream>>>(x0, x1, xb);

  // weight transposes (64x64 vectorized)
  convtrans64<<<dim3(32, 4, 32), 256, 0, stream>>>(qg_w0, qg_w1, qsc, wbuf, WD_, 256, 16);
  convtrans64<<<dim3(32, 2, 8), 256, 0, stream>>>(k_w0, k_w1, k0t, k1t, WD_, 128, 4);
  convtrans64<<<dim3(32, 2, 8), 256, 0, stream>>>(v_w0, v_w1, v0t, v1t, WD_, 128, 4);

  // all projections, one launch
  gemm_proj<<<dim3(40, 16), 256, 0, stream>>>(xb, qsc, wbuf, k0t, k1t, v0t, v1t,
                                              qgb, kcache, vcache);

  // norm + rope (kcache in place -> cached_k; Kb bf16 into xb alias)
  // + fused V transpose: Vt (kh*128+h, t) bf16 from vcache
  postproc_vt<<<2304, 256, 0, stream>>>(qgb, kcache, Kbuf, pos, qn0, kn0, qn1, kn1,
                                        vcache, Vtb);

  attn<<<dim3(32, 16), 256, 0, stream>>>(qgb, Kbuf, Vtb, encb);

  // output projection
  convtrans64<<<dim3(32, 32, 2), 256, 0, stream>>>(o_w0, o_w1, wbuf, wbuf + 4194304, WD_, WD_, 1);
  gemm_out<<<dim3(16, 16), 256, 0, stream>>>(encb, wbuf, wbuf + 4194304, out);
}

// Round 6
// 363.681 us; speedup vs baseline: 1.1189x; 1.0278x over previous
//
#include <hip/hip_runtime.h>
#include <hip/hip_bf16.h>
#include <cstdint>
#include <cstddef>

#define T0_ 512
#define TT_ 2048
#define WD_ 2048
#define NH_ 16
#define KH_ 4

typedef __attribute__((ext_vector_type(8))) short short8;
typedef __attribute__((ext_vector_type(4))) short short4v;
typedef __attribute__((ext_vector_type(4))) float f32x4;

#define AS1 __attribute__((address_space(1)))
#define AS3 __attribute__((address_space(3)))

__device__ __forceinline__ ushort f2bf(float x) {
  __hip_bfloat16 h = __float2bfloat16(x);
  ushort u; __builtin_memcpy(&u, &h, 2); return u;
}
__device__ __forceinline__ float bf2f(ushort u) {
  __hip_bfloat16 h; __builtin_memcpy(&h, &u, 2);
  return __bfloat162float(h);
}
__device__ __forceinline__ void g2l16(const ushort* g, AS3 ushort* s) {
  __builtin_amdgcn_global_load_lds((const AS1 uint32_t*)g, (AS3 uint32_t*)s, 16, 0, 0);
}

// ---------------------------------------------------------------------------
// Merged prep: convert_x + qg/k/v weight transposes, one launch.
// blocks [0,4096): x0/x1 f32 -> xb bf16
// blocks [4096,8192): qg transpose (32 rt x 4 ct x 32 z)
// blocks [8192,8704): k transpose  (32 rt x 2 ct x 8 z)
// blocks [8704,9216): v transpose  (32 rt x 2 ct x 8 z)
// Transpose: 64x64 tile, float4 reads, LDS staged transposed (stride 67),
// ushort4 stores.
__global__ __launch_bounds__(256) void prep(
    const float* __restrict__ x0, const float* __restrict__ x1, ushort* __restrict__ xb,
    const float* __restrict__ qg_w0, const float* __restrict__ qg_w1,
    ushort* __restrict__ qg0t, ushort* __restrict__ qg1t,
    const float* __restrict__ k_w0, const float* __restrict__ k_w1,
    ushort* __restrict__ k0t, ushort* __restrict__ k1t,
    const float* __restrict__ v_w0, const float* __restrict__ v_w1,
    ushort* __restrict__ v0t, ushort* __restrict__ v1t)
{
  __shared__ float tile[64][67];
  int b = blockIdx.x;
  if (b < 4096) {  // convert_x
    const int i = b * 256 + threadIdx.x;
    const int e = i * 4;
    const int row = e >> 11, col = e & 2047;
    const float* src = (row < T0_) ? (x0 + (size_t)row * WD_ + col)
                                   : (x1 + (size_t)(row - T0_) * WD_ + col);
    const float4 v = *(const float4*)src;
    ushort4 o; o.x = f2bf(v.x); o.y = f2bf(v.y); o.z = f2bf(v.z); o.w = f2bf(v.w);
    *(ushort4*)(xb + e) = o;
    return;
  }
  b -= 4096;
  const float* in; ushort* out; int C, rt, ct;
  if (b < 4096) {            // qg: R=2048, C=256
    const int z = b >> 7, rem = b & 127; rt = rem & 31; ct = rem >> 5; C = 256;
    if (z < 16) { in = qg_w0 + (size_t)z * WD_ * 256; out = qg0t + (size_t)z * WD_ * 256; }
    else { in = qg_w1 + (size_t)(z - 16) * WD_ * 256; out = qg1t + (size_t)(z - 16) * WD_ * 256; }
  } else if (b < 4608) {     // k: R=2048, C=128
    b -= 4096;
    const int z = b >> 6, rem = b & 63; rt = rem & 31; ct = rem >> 5; C = 128;
    if (z < 4) { in = k_w0 + (size_t)z * WD_ * 128; out = k0t + (size_t)z * WD_ * 128; }
    else { in = k_w1 + (size_t)(z - 4) * WD_ * 128; out = k1t + (size_t)(z - 4) * WD_ * 128; }
  } else {                   // v
    b -= 4608;
    const int z = b >> 6, rem = b & 63; rt = rem & 31; ct = rem >> 5; C = 128;
    if (z < 4) { in = v_w0 + (size_t)z * WD_ * 128; out = v0t + (size_t)z * WD_ * 128; }
    else { in = v_w1 + (size_t)(z - 4) * WD_ * 128; out = v1t + (size_t)(z - 4) * WD_ * 128; }
  }
  const int r0 = rt * 64, c0 = ct * 64;
  const int cx = threadIdx.x & 15, ry = threadIdx.x >> 4;
#pragma unroll
  for (int i = 0; i < 4; ++i) {
    const int r = ry + i * 16;
    const float4 v = *(const float4*)&in[(size_t)(r0 + r) * C + c0 + cx * 4];
    tile[cx * 4 + 0][r] = v.x;
    tile[cx * 4 + 1][r] = v.y;
    tile[cx * 4 + 2][r] = v.z;
    tile[cx * 4 + 3][r] = v.w;
  }
  __syncthreads();
  const int rq = threadIdx.x & 15, cy = threadIdx.x >> 4;
#pragma unroll
  for (int i = 0; i < 4; ++i) {
    const int c = cy + i * 16;
    ushort4 o;
    o.x = f2bf(tile[c][rq * 4 + 0]);
    o.y = f2bf(tile[c][rq * 4 + 1]);
    o.z = f2bf(tile[c][rq * 4 + 2]);
    o.w = f2bf(tile[c][rq * 4 + 3]);
    *(ushort4*)&out[(size_t)(c0 + c) * WD_ + r0 + rq * 4] = o;
  }
}

// ---------------------------------------------------------------------------
// 64x64 transpose-convert (o_w only now): in f32 (slab,R,C) -> out bf16 (slab,C,R)
__global__ __launch_bounds__(256) void convtrans64(
    const float* __restrict__ s0, const float* __restrict__ s1,
    ushort* __restrict__ d0, ushort* __restrict__ d1, int R, int C, int half)
{
  __shared__ float tile[64][67];
  int z = blockIdx.z;
  const float* in; ushort* out;
  if (z < half) { in = s0 + (size_t)z * R * C; out = d0 + (size_t)z * R * C; }
  else { z -= half; in = s1 + (size_t)z * R * C; out = d1 + (size_t)z * R * C; }
  const int r0 = blockIdx.x * 64, c0 = blockIdx.y * 64;
  const int cx = threadIdx.x & 15, ry = threadIdx.x >> 4;
#pragma unroll
  for (int i = 0; i < 4; ++i) {
    const int r = ry + i * 16;
    const float4 v = *(const float4*)&in[(size_t)(r0 + r) * C + c0 + cx * 4];
    tile[cx * 4 + 0][r] = v.x;
    tile[cx * 4 + 1][r] = v.y;
    tile[cx * 4 + 2][r] = v.z;
    tile[cx * 4 + 3][r] = v.w;
  }
  __syncthreads();
  const int rq = threadIdx.x & 15, cy = threadIdx.x >> 4;
#pragma unroll
  for (int i = 0; i < 4; ++i) {
    const int c = cy + i * 16;
    ushort4 o;
    o.x = f2bf(tile[c][rq * 4 + 0]);
    o.y = f2bf(tile[c][rq * 4 + 1]);
    o.z = f2bf(tile[c][rq * 4 + 2]);
    o.w = f2bf(tile[c][rq * 4 + 3]);
    *(ushort4*)&out[(size_t)(c0 + c) * R + r0 + rq * 4] = o;
  }
}

// ---------------------------------------------------------------------------
// Shared MFMA GEMM core (PROVEN): 128x128 C tile, BK=64, double-buffered LDS
// (64 KiB -> 2 blocks/CU), issue-early stage, one __syncthreads per K-step.
// Chunk-XOR swizzle (conflicts measured 0).
__device__ __forceinline__ void gemm_core(
    const ushort* __restrict__ A, const ushort* __restrict__ Bt,
    int row0, int col0, ushort* As, ushort* Bs, f32x4 (&acc)[4][4])
{
  const int tid = threadIdx.x;
  const int w = tid >> 6, l = tid & 63, lq = l >> 4, lm = l & 15;
  const int wr = (w >> 1) * 64, wc = (w & 1) * 64;
  const int sx = lm & 7;                               // read-swizzle key
  const int gsw = (tid & 7) ^ ((tid >> 3) & 7);        // pre-swizzled source chunk
  const ushort* Ag = A + (size_t)(row0 + (tid >> 3)) * WD_ + gsw * 8;
  const ushort* Bg = Bt + (size_t)(col0 + (tid >> 3)) * WD_ + gsw * 8;
  AS3 ushort* AsW = (AS3 ushort*)As + w * 512;
  AS3 ushort* BsW = (AS3 ushort*)Bs + w * 512;

  auto stage = [&](int buf, int k0) {
#pragma unroll
    for (int c = 0; c < 4; ++c) {
      g2l16(Ag + (size_t)(c * 32) * WD_ + k0, AsW + buf * 8192 + c * 2048);
      g2l16(Bg + (size_t)(c * 32) * WD_ + k0, BsW + buf * 8192 + c * 2048);
    }
  };

  stage(0, 0);
  __syncthreads();
  int buf = 0;
  for (int k0 = 0; k0 < WD_; k0 += 64) {
    if (k0 + 64 < WD_) stage(buf ^ 1, k0 + 64);
    const ushort* Ab = As + buf * 8192;
    const ushort* Bb = Bs + buf * 8192;
#pragma unroll
    for (int kk = 0; kk < 2; ++kk) {
      short8 af[4], bfr[4];
#pragma unroll
      for (int mi = 0; mi < 4; ++mi)
        af[mi] = *(const short8*)&Ab[(wr + mi * 16 + lm) * 64 + (((kk * 4 + lq) ^ sx) << 3)];
#pragma unroll
      for (int ni = 0; ni < 4; ++ni)
        bfr[ni] = *(const short8*)&Bb[(wc + ni * 16 + lm) * 64 + (((kk * 4 + lq) ^ sx) << 3)];
#pragma unroll
      for (int mi = 0; mi < 4; ++mi)
#pragma unroll
        for (int ni = 0; ni < 4; ++ni)
          acc[mi][ni] = __builtin_amdgcn_mfma_f32_16x16x32_bf16(af[mi], bfr[ni], acc[mi][ni], 0, 0, 0);
    }
    __syncthreads();
    buf ^= 1;
  }
}

// ---------------------------------------------------------------------------
// All projections in one launch. grid (40, 16):
//  bx<32: qg (bf16, ldc 4096) | bx 32..35: k->kcache f32 | bx 36..39: v->vcache f32
__global__ __launch_bounds__(256) void gemm_proj(
    const ushort* __restrict__ A,
    const ushort* __restrict__ qg0t, const ushort* __restrict__ qg1t,
    const ushort* __restrict__ k0t,  const ushort* __restrict__ k1t,
    const ushort* __restrict__ v0t,  const ushort* __restrict__ v1t,
    ushort* __restrict__ Cqg, float* __restrict__ kc, float* __restrict__ vc)
{
  __shared__ ushort As[16384], Bs[16384];
  const int bx = blockIdx.x;
  const int row0 = blockIdx.y * 128;
  const bool s1 = (row0 >= T0_);
  const ushort* Bt; int col0;
  float* Cf = nullptr; ushort* Cb = nullptr; int ldc;
  if (bx < 32) {
    Bt = s1 ? qg1t : qg0t; col0 = bx * 128; Cb = Cqg; ldc = 4096;
  } else if (bx < 36) {
    Bt = s1 ? k1t : k0t; col0 = (bx - 32) * 128; Cf = kc; ldc = 512;
  } else {
    Bt = s1 ? v1t : v0t; col0 = (bx - 36) * 128; Cf = vc; ldc = 512;
  }
  f32x4 acc[4][4];
#pragma unroll
  for (int mi = 0; mi < 4; ++mi)
#pragma unroll
    for (int ni = 0; ni < 4; ++ni) acc[mi][ni] = (f32x4){0.f, 0.f, 0.f, 0.f};
  gemm_core(A, Bt, row0, col0, As, Bs, acc);
  const int w = threadIdx.x >> 6, l = threadIdx.x & 63, lq = l >> 4, lm = l & 15;
  const int wr = (w >> 1) * 64, wc = (w & 1) * 64;
#pragma unroll
  for (int mi = 0; mi < 4; ++mi)
#pragma unroll
    for (int ni = 0; ni < 4; ++ni)
#pragma unroll
      for (int r = 0; r < 4; ++r) {
        const size_t rr = (size_t)row0 + wr + mi * 16 + lq * 4 + r;
        const size_t cc = (size_t)col0 + wc + ni * 16 + lm;
        if (Cb) Cb[rr * ldc + cc] = f2bf(acc[mi][ni][r]);
        else    Cf[rr * ldc + cc] = acc[mi][ni][r];
      }
}

// ---------------------------------------------------------------------------
// out projection, 128x64 tiles: grid (32, 16) = 512 blocks -> 2 blocks/CU
// co-residency (the 1-block/CU 128x128 version had zero overlap and was
// latency-exposed). LDS 48 KiB. Same staging/swizzle algebra, BN=64.
__global__ __launch_bounds__(256) void gemm_out(
    const ushort* __restrict__ A, const ushort* __restrict__ W0t,
    const ushort* __restrict__ W1t, float* __restrict__ C)
{
  __shared__ ushort As[2 * 8192], Bs[2 * 4096];
  const int row0 = blockIdx.y * 128, col0 = blockIdx.x * 64;
  const ushort* Bt = (row0 < T0_) ? W0t : W1t;
  const int tid = threadIdx.x;
  const int w = tid >> 6, l = tid & 63, lq = l >> 4, lm = l & 15;
  const int wr = (w >> 1) * 64, wc = (w & 1) * 32;
  const int sx = lm & 7;
  const int gsw = (tid & 7) ^ ((tid >> 3) & 7);
  const ushort* Ag = A + (size_t)(row0 + (tid >> 3)) * WD_ + gsw * 8;
  const ushort* Bg = Bt + (size_t)(col0 + (tid >> 3)) * WD_ + gsw * 8;
  AS3 ushort* AsW = (AS3 ushort*)As + w * 512;
  AS3 ushort* BsW = (AS3 ushort*)Bs + w * 512;

  f32x4 acc[4][2];
#pragma unroll
  for (int mi = 0; mi < 4; ++mi)
#pragma unroll
    for (int ni = 0; ni < 2; ++ni) acc[mi][ni] = (f32x4){0.f, 0.f, 0.f, 0.f};

  auto stage = [&](int buf, int k0) {
#pragma unroll
    for (int c = 0; c < 4; ++c)
      g2l16(Ag + (size_t)(c * 32) * WD_ + k0, AsW + buf * 8192 + c * 2048);
#pragma unroll
    for (int c = 0; c < 2; ++c)
      g2l16(Bg + (size_t)(c * 32) * WD_ + k0, BsW + buf * 4096 + c * 2048);
  };

  stage(0, 0);
  __syncthreads();
  int buf = 0;
  for (int k0 = 0; k0 < WD_; k0 += 64) {
    if (k0 + 64 < WD_) stage(buf ^ 1, k0 + 64);
    const ushort* Ab = As + buf * 8192;
    const ushort* Bb = Bs + buf * 4096;
#pragma unroll
    for (int kk = 0; kk < 2; ++kk) {
      short8 af[4], bfr[2];
#pragma unroll
      for (int mi = 0; mi < 4; ++mi)
        af[mi] = *(const short8*)&Ab[(wr + mi * 16 + lm) * 64 + (((kk * 4 + lq) ^ sx) << 3)];
#pragma unroll
      for (int ni = 0; ni < 2; ++ni)
        bfr[ni] = *(const short8*)&Bb[(wc + ni * 16 + lm) * 64 + (((kk * 4 + lq) ^ sx) << 3)];
#pragma unroll
      for (int mi = 0; mi < 4; ++mi)
#pragma unroll
        for (int ni = 0; ni < 2; ++ni)
          acc[mi][ni] = __builtin_amdgcn_mfma_f32_16x16x32_bf16(af[mi], bfr[ni], acc[mi][ni], 0, 0, 0);
    }
    __syncthreads();
    buf ^= 1;
  }
#pragma unroll
  for (int mi = 0; mi < 4; ++mi)
#pragma unroll
    for (int ni = 0; ni < 2; ++ni)
#pragma unroll
      for (int r = 0; r < 4; ++r) {
        const size_t rr = (size_t)row0 + wr + mi * 16 + lq * 4 + r;
        const size_t cc = (size_t)col0 + wc + ni * 16 + lm;
        C[rr * 2048 + cc] = acc[mi][ni][r];
      }
}

// ---------------------------------------------------------------------------
// Fused: RMSNorm + RoPE (+ q scale)  [blocks 0..2047]
//        V transpose vcache f32 (2048,512) -> Vtb bf16 (512,2048), 64x64 tiles
//        [blocks 2048..2303]
__global__ __launch_bounds__(256) void postproc_vt(
    ushort* __restrict__ qgb, float* __restrict__ kc, ushort* __restrict__ Kb,
    const int* __restrict__ positions,
    const float* __restrict__ qn0, const float* __restrict__ kn0,
    const float* __restrict__ qn1, const float* __restrict__ kn1,
    const float* __restrict__ vcache, ushort* __restrict__ Vtb)
{
  __shared__ float tile[64][67];
  if (blockIdx.x >= 2048) {
    const int idx = blockIdx.x - 2048;           // 32 r-tiles x 8 c-tiles
    const int r0 = (idx & 31) * 64, c0 = (idx >> 5) * 64;
    const int cx = threadIdx.x & 15, ry = threadIdx.x >> 4;
#pragma unroll
    for (int i = 0; i < 4; ++i) {
      const int r = ry + i * 16;
      const float4 v = *(const float4*)&vcache[(size_t)(r0 + r) * 512 + c0 + cx * 4];
      tile[cx * 4 + 0][r] = v.x;
      tile[cx * 4 + 1][r] = v.y;
      tile[cx * 4 + 2][r] = v.z;
      tile[cx * 4 + 3][r] = v.w;
    }
    __syncthreads();
    const int rq = threadIdx.x & 15, cy = threadIdx.x >> 4;
#pragma unroll
    for (int i = 0; i < 4; ++i) {
      const int c = cy + i * 16;
      ushort4 o;
      o.x = f2bf(tile[c][rq * 4 + 0]);
      o.y = f2bf(tile[c][rq * 4 + 1]);
      o.z = f2bf(tile[c][rq * 4 + 2]);
      o.w = f2bf(tile[c][rq * 4 + 3]);
      *(ushort4*)&Vtb[(size_t)(c0 + c) * 2048 + r0 + rq * 4] = o;
    }
    return;
  }
  const int t = blockIdx.x;
  const int w = threadIdx.x >> 6, l = threadIdx.x & 63;
  const float pos = (float)positions[t];
  const bool str1 = (t >= T0_);
  const float* qn = str1 ? qn1 : qn0;
  const float* kn = str1 ? kn1 : kn0;
  const float kfreq = 13.815510557964274f / 32.0f;  // ln(1e6)/32
  const int h0 = 2 * l, h1 = 2 * l + 1;

  for (int r = w; r < NH_ + KH_; r += 4) {
    const bool isq = (r < NH_);
    float v0, v1; size_t bi; const float* sc;
    if (isq) {
      bi = ((size_t)t * NH_ + r) * 256;
      v0 = bf2f(qgb[bi + h0]); v1 = bf2f(qgb[bi + h1]); sc = qn;
    } else {
      bi = ((size_t)t * KH_ + (r - NH_)) * 128;
      v0 = kc[bi + h0]; v1 = kc[bi + h1]; sc = kn;
    }
    float ss = v0 * v0 + v1 * v1;
#pragma unroll
    for (int off = 32; off > 0; off >>= 1) ss += __shfl_xor(ss, off);
    const float rstd = rsqrtf(ss * (1.0f / 128.0f) + 1e-6f);
    v0 = v0 * rstd * (1.0f + sc[h0]);
    v1 = v1 * rstd * (1.0f + sc[h1]);
    const float p0 = __shfl_xor(v0, 16);
    const float p1 = __shfl_xor(v1, 16);
    if (l < 32) {
      const int i0 = (l < 16) ? h0 : (h0 - 32);
      const float a0 = pos * __expf(-(float)i0 * kfreq);
      const float a1 = pos * __expf(-(float)(i0 + 1) * kfreq);
      const float c0 = cosf(a0), s0 = sinf(a0);
      const float c1 = cosf(a1), s1v = sinf(a1);
      if (l < 16) { v0 = v0 * c0 - p0 * s0; v1 = v1 * c1 - p1 * s1v; }
      else        { v0 = v0 * c0 + p0 * s0; v1 = v1 * c1 + p1 * s1v; }
    }
    if (isq) {
      v0 *= 0.08838834764831843f; v1 *= 0.08838834764831843f;
      qgb[bi + h0] = f2bf(v0); qgb[bi + h1] = f2bf(v1);
    } else {
      kc[bi + h0] = v0; kc[bi + h1] = v1;
      Kb[bi + h0] = f2bf(v0); Kb[bi + h1] = f2bf(v1);
    }
  }
}

// ---------------------------------------------------------------------------
// Flash attention, S^T formulation, XOR-swizzled LDS. SB=64 s-step ->
// LDS 72 KiB -> 2 blocks/CU. Grid (32, 16): one qt tile per block,
// qt = (n<8) ? bx : 31-bx so co-scheduled block pairs sum to ~equal work.
// qgb: normed q + raw gate bf16 (t,n,256); Kb (t,kh,128); Vt (kh,128,2048).
__global__ __launch_bounds__(256) void attn(
    const ushort* __restrict__ qgb, const ushort* __restrict__ Kb,
    const ushort* __restrict__ Vt, ushort* __restrict__ encb)
{
  __shared__ ushort Ks[2 * 8192];  // [buf][s 0..63][h 0..127], 16B chunks ^ (s&15)
  __shared__ ushort Vs[2 * 8192];  // [buf][h 0..127][s 0..63],  16B chunks ^ (h&7)
  __shared__ ushort Ps[4 * 1024];  // per-wave [q 0..15][s 0..63], 8B units ^ lm
  const int tid = threadIdx.x;
  const int w = tid >> 6, l = tid & 63, lq = l >> 4, lm = l & 15;
  const int n = blockIdx.y, kh = n >> 2;
  const int qt = (n < 8) ? (int)blockIdx.x : (31 - (int)blockIdx.x);
  const int qtb = qt * 64;
  const int nst = qt + 1;          // 64-wide s-steps

  auto stage = [&](int buf, int s0) {
#pragma unroll
    for (int c = 0; c < 4; ++c) {
      {
        const int base = c * 16 + w * 4;          // K s-row base
        const int row = base + (l >> 4);
        const int j = l & 15;
        g2l16(Kb + (size_t)(s0 + row) * 512 + kh * 128 + (j ^ (row & 15)) * 8,
              (AS3 ushort*)Ks + buf * 8192 + base * 128);
      }
      {
        const int base = c * 32 + w * 8;          // V h-row base
        const int row = base + (l >> 3);
        const int j = l & 7;
        g2l16(Vt + (size_t)(kh * 128 + row) * 2048 + s0 + (j ^ (row & 7)) * 8,
              (AS3 ushort*)Vs + buf * 8192 + base * 64);
      }
    }
  };

  short8 aq[4];
  {
    const ushort* qb = qgb + ((size_t)(qtb + w * 16 + lm) * NH_ + n) * 256 + lq * 8;
#pragma unroll
    for (int kk = 0; kk < 4; ++kk) aq[kk] = *(const short8*)(qb + kk * 32);
  }
  f32x4 acc[8];
#pragma unroll
  for (int i = 0; i < 8; ++i) acc[i] = (f32x4){0.f, 0.f, 0.f, 0.f};
  float mq = -3.0e38f, lsum = 0.0f;

  stage(0, 0);

  for (int st = 0; st < nst; ++st) {
    const int buf = st & 1;
    const int s0 = st * 64;
    __syncthreads();
    if (st + 1 < nst) stage(buf ^ 1, s0 + 64);
    const ushort* Kt = Ks + buf * 8192;
    const ushort* Vb = Vs + buf * 8192;

    // S^T = K * Q^T : D[m=s][n=q]
    f32x4 sa[4];
#pragma unroll
    for (int mi = 0; mi < 4; ++mi) sa[mi] = (f32x4){0.f, 0.f, 0.f, 0.f};
#pragma unroll
    for (int kk = 0; kk < 4; ++kk)
#pragma unroll
      for (int mi = 0; mi < 4; ++mi) {
        const short8 ak = *(const short8*)&Kt[(mi * 16 + lm) * 128 + ((kk * 4 + lq) ^ lm) * 8];
        sa[mi] = __builtin_amdgcn_mfma_f32_16x16x32_bf16(ak, aq[kk], sa[mi], 0, 0, 0);
      }
    if (s0 + 63 > qtb) {
      const int qg_ = qtb + w * 16 + lm;
#pragma unroll
      for (int mi = 0; mi < 4; ++mi)
#pragma unroll
        for (int r = 0; r < 4; ++r)
          if (s0 + mi * 16 + lq * 4 + r > qg_) sa[mi][r] = -3.0e38f;
    }
    float mx = sa[0][0];
#pragma unroll
    for (int mi = 0; mi < 4; ++mi)
#pragma unroll
      for (int r = 0; r < 4; ++r) mx = fmaxf(mx, sa[mi][r]);
    mx = fmaxf(mx, __shfl_xor(mx, 16));
    mx = fmaxf(mx, __shfl_xor(mx, 32));
    const float mn = fmaxf(mq, mx);
    const float alpha = __expf(mq - mn);
    mq = mn;
    float sl = 0.0f;
#pragma unroll
    for (int mi = 0; mi < 4; ++mi)
#pragma unroll
      for (int r = 0; r < 4; ++r) {
        const float p = __expf(sa[mi][r] - mn);
        sa[mi][r] = p; sl += p;
      }
    sl += __shfl_xor(sl, 16);
    sl += __shfl_xor(sl, 32);
    lsum = lsum * alpha + sl;

#pragma unroll
    for (int mi = 0; mi < 4; ++mi) {
      short4v pw;
#pragma unroll
      for (int r = 0; r < 4; ++r) pw[r] = (short)f2bf(sa[mi][r]);
      *(short4v*)&Ps[w * 1024 + lm * 64 + ((mi * 4 + lq) ^ lm) * 4] = pw;
    }
    float aP[4];
#pragma unroll
    for (int r = 0; r < 4; ++r) aP[r] = __shfl(alpha, lq * 4 + r);
#pragma unroll
    for (int hi = 0; hi < 8; ++hi) {
      f32x4 a = acc[hi];
#pragma unroll
      for (int r = 0; r < 4; ++r) a[r] *= aP[r];
      acc[hi] = a;
    }
#pragma unroll
    for (int mi2 = 0; mi2 < 2; ++mi2) {
      const short4v pa = *(const short4v*)&Ps[w * 1024 + lm * 64 + ((mi2 * 8 + lq * 2 + 0) ^ lm) * 4];
      const short4v pb = *(const short4v*)&Ps[w * 1024 + lm * 64 + ((mi2 * 8 + lq * 2 + 1) ^ lm) * 4];
      const short8 ap = __builtin_shufflevector(pa, pb, 0, 1, 2, 3, 4, 5, 6, 7);
#pragma unroll
      for (int hi = 0; hi < 8; ++hi) {
        const short8 bv = *(const short8*)&Vb[(hi * 16 + lm) * 64 + (((mi2 * 4 + lq) ^ (lm & 7)) << 3)];
        acc[hi] = __builtin_amdgcn_mfma_f32_16x16x32_bf16(ap, bv, acc[hi], 0, 0, 0);
      }
    }
  }
  const float linv = 1.0f / lsum;
  float lP[4];
#pragma unroll
  for (int r = 0; r < 4; ++r) lP[r] = __shfl(linv, lq * 4 + r);
#pragma unroll
  for (int hi = 0; hi < 8; ++hi)
#pragma unroll
    for (int r = 0; r < 4; ++r) {
      const int t = qtb + w * 16 + lq * 4 + r;
      const int h = hi * 16 + lm;
      const float g = bf2f(qgb[((size_t)t * NH_ + n) * 256 + 128 + h]);
      const float o = acc[hi][r] * lP[r] * (1.0f / (1.0f + __expf(-g)));
      encb[((size_t)t * NH_ + n) * 128 + h] = f2bf(o);
    }
}

// ---------------------------------------------------------------------------
extern "C" void kernel_launch(void* const* d_in, const int* in_sizes, int n_in,
                              void* d_out, int out_size, void* d_ws, size_t ws_size,
                              hipStream_t stream)
{
  (void)in_sizes; (void)n_in; (void)out_size; (void)ws_size;
  const float* x0    = (const float*)d_in[0];
  const float* x1    = (const float*)d_in[1];
  const int*   pos   = (const int*)d_in[2];
  const float* qg_w0 = (const float*)d_in[4];
  const float* k_w0  = (const float*)d_in[5];
  const float* v_w0  = (const float*)d_in[6];
  const float* qn0   = (const float*)d_in[7];
  const float* kn0   = (const float*)d_in[8];
  const float* o_w0  = (const float*)d_in[9];
  const float* qg_w1 = (const float*)d_in[10];
  const float* k_w1  = (const float*)d_in[11];
  const float* v_w1  = (const float*)d_in[12];
  const float* qn1   = (const float*)d_in[13];
  const float* kn1   = (const float*)d_in[14];
  const float* o_w1  = (const float*)d_in[15];

  float* out    = (float*)d_out;
  float* kcache = out + (size_t)TT_ * WD_;
  float* vcache = kcache + (size_t)TT_ * KH_ * 128;
  ushort* qsc = (ushort*)d_out;  // out0/out1 region doubles as qg_w0^T scratch

  // ws: wbuf 16M | xb 8M (-> Kb 2M + Vt 2M after projections) | qgb 16M | encb 8M
  ushort* wbuf = (ushort*)d_ws;
  ushort* xb   = wbuf + 8388608;
  ushort* qgb  = xb + 4194304;
  ushort* encb = qgb + 8388608;
  ushort* Kbuf = xb;
  ushort* Vtb  = xb + 1048576;
  ushort* k0t = encb, *k1t = encb + 1048576, *v0t = encb + 2097152, *v1t = encb + 3145728;

  // merged convert + qg/k/v transposes
  prep<<<9216, 256, 0, stream>>>(x0, x1, xb,
                                 qg_w0, qg_w1, qsc, wbuf,
                                 k_w0, k_w1, k0t, k1t,
                                 v_w0, v_w1, v0t, v1t);

  // all projections, one launch
  gemm_proj<<<dim3(40, 16), 256, 0, stream>>>(xb, qsc, wbuf, k0t, k1t, v0t, v1t,
                                              qgb, kcache, vcache);

  // norm + rope (kcache in place -> cached_k; Kb bf16 into xb alias)
  // + fused V transpose: Vt (kh*128+h, t) bf16 from vcache
  postproc_vt<<<2304, 256, 0, stream>>>(qgb, kcache, Kbuf, pos, qn0, kn0, qn1, kn1,
                                        vcache, Vtb);

  attn<<<dim3(32, 16), 256, 0, stream>>>(qgb, Kbuf, Vtb, encb);

  // output projection
  convtrans64<<<dim3(32, 32, 2), 256, 0, stream>>>(o_w0, o_w1, wbuf, wbuf + 4194304, WD_, WD_, 1);
  gemm_out<<<dim3(32, 16), 256, 0, stream>>>(encb, wbuf, wbuf + 4194304, out);
}

// Round 7
// 350.349 us; speedup vs baseline: 1.1615x; 1.0381x over previous
//
#include <hip/hip_runtime.h>
#include <hip/hip_bf16.h>
#include <cstdint>
#include <cstddef>

#define T0_ 512
#define TT_ 2048
#define WD_ 2048
#define NH_ 16
#define KH_ 4

typedef __attribute__((ext_vector_type(8))) short short8;
typedef __attribute__((ext_vector_type(4))) short short4v;
typedef __attribute__((ext_vector_type(4))) float f32x4;

#define AS1 __attribute__((address_space(1)))
#define AS3 __attribute__((address_space(3)))

__device__ __forceinline__ ushort f2bf(float x) {
  __hip_bfloat16 h = __float2bfloat16(x);
  ushort u; __builtin_memcpy(&u, &h, 2); return u;
}
__device__ __forceinline__ float bf2f(ushort u) {
  __hip_bfloat16 h; __builtin_memcpy(&h, &u, 2);
  return __bfloat162float(h);
}
__device__ __forceinline__ void g2l16(const ushort* g, AS3 ushort* s) {
  __builtin_amdgcn_global_load_lds((const AS1 uint32_t*)g, (AS3 uint32_t*)s, 16, 0, 0);
}

// ---------------------------------------------------------------------------
// Merged prep: convert_x + qg/k/v weight transposes, one launch.
// blocks [0,4096): x0/x1 f32 -> xb bf16
// blocks [4096,8192): qg transpose (32 rt x 4 ct x 32 z)
// blocks [8192,8704): k transpose  (32 rt x 2 ct x 8 z)
// blocks [8704,9216): v transpose  (32 rt x 2 ct x 8 z)
__global__ __launch_bounds__(256) void prep(
    const float* __restrict__ x0, const float* __restrict__ x1, ushort* __restrict__ xb,
    const float* __restrict__ qg_w0, const float* __restrict__ qg_w1,
    ushort* __restrict__ qg0t, ushort* __restrict__ qg1t,
    const float* __restrict__ k_w0, const float* __restrict__ k_w1,
    ushort* __restrict__ k0t, ushort* __restrict__ k1t,
    const float* __restrict__ v_w0, const float* __restrict__ v_w1,
    ushort* __restrict__ v0t, ushort* __restrict__ v1t)
{
  __shared__ float tile[64][67];
  int b = blockIdx.x;
  if (b < 4096) {  // convert_x
    const int i = b * 256 + threadIdx.x;
    const int e = i * 4;
    const int row = e >> 11, col = e & 2047;
    const float* src = (row < T0_) ? (x0 + (size_t)row * WD_ + col)
                                   : (x1 + (size_t)(row - T0_) * WD_ + col);
    const float4 v = *(const float4*)src;
    ushort4 o; o.x = f2bf(v.x); o.y = f2bf(v.y); o.z = f2bf(v.z); o.w = f2bf(v.w);
    *(ushort4*)(xb + e) = o;
    return;
  }
  b -= 4096;
  const float* in; ushort* out; int C, rt, ct;
  if (b < 4096) {            // qg: R=2048, C=256
    const int z = b >> 7, rem = b & 127; rt = rem & 31; ct = rem >> 5; C = 256;
    if (z < 16) { in = qg_w0 + (size_t)z * WD_ * 256; out = qg0t + (size_t)z * WD_ * 256; }
    else { in = qg_w1 + (size_t)(z - 16) * WD_ * 256; out = qg1t + (size_t)(z - 16) * WD_ * 256; }
  } else if (b < 4608) {     // k: R=2048, C=128
    b -= 4096;
    const int z = b >> 6, rem = b & 63; rt = rem & 31; ct = rem >> 5; C = 128;
    if (z < 4) { in = k_w0 + (size_t)z * WD_ * 128; out = k0t + (size_t)z * WD_ * 128; }
    else { in = k_w1 + (size_t)(z - 4) * WD_ * 128; out = k1t + (size_t)(z - 4) * WD_ * 128; }
  } else {                   // v
    b -= 4608;
    const int z = b >> 6, rem = b & 63; rt = rem & 31; ct = rem >> 5; C = 128;
    if (z < 4) { in = v_w0 + (size_t)z * WD_ * 128; out = v0t + (size_t)z * WD_ * 128; }
    else { in = v_w1 + (size_t)(z - 4) * WD_ * 128; out = v1t + (size_t)(z - 4) * WD_ * 128; }
  }
  const int r0 = rt * 64, c0 = ct * 64;
  const int cx = threadIdx.x & 15, ry = threadIdx.x >> 4;
#pragma unroll
  for (int i = 0; i < 4; ++i) {
    const int r = ry + i * 16;
    const float4 v = *(const float4*)&in[(size_t)(r0 + r) * C + c0 + cx * 4];
    tile[cx * 4 + 0][r] = v.x;
    tile[cx * 4 + 1][r] = v.y;
    tile[cx * 4 + 2][r] = v.z;
    tile[cx * 4 + 3][r] = v.w;
  }
  __syncthreads();
  const int rq = threadIdx.x & 15, cy = threadIdx.x >> 4;
#pragma unroll
  for (int i = 0; i < 4; ++i) {
    const int c = cy + i * 16;
    ushort4 o;
    o.x = f2bf(tile[c][rq * 4 + 0]);
    o.y = f2bf(tile[c][rq * 4 + 1]);
    o.z = f2bf(tile[c][rq * 4 + 2]);
    o.w = f2bf(tile[c][rq * 4 + 3]);
    *(ushort4*)&out[(size_t)(c0 + c) * WD_ + r0 + rq * 4] = o;
  }
}

// ---------------------------------------------------------------------------
// 64x64 transpose-convert (o_w only): in f32 (slab,R,C) -> out bf16 (slab,C,R)
__global__ __launch_bounds__(256) void convtrans64(
    const float* __restrict__ s0, const float* __restrict__ s1,
    ushort* __restrict__ d0, ushort* __restrict__ d1, int R, int C, int half)
{
  __shared__ float tile[64][67];
  int z = blockIdx.z;
  const float* in; ushort* out;
  if (z < half) { in = s0 + (size_t)z * R * C; out = d0 + (size_t)z * R * C; }
  else { z -= half; in = s1 + (size_t)z * R * C; out = d1 + (size_t)z * R * C; }
  const int r0 = blockIdx.x * 64, c0 = blockIdx.y * 64;
  const int cx = threadIdx.x & 15, ry = threadIdx.x >> 4;
#pragma unroll
  for (int i = 0; i < 4; ++i) {
    const int r = ry + i * 16;
    const float4 v = *(const float4*)&in[(size_t)(r0 + r) * C + c0 + cx * 4];
    tile[cx * 4 + 0][r] = v.x;
    tile[cx * 4 + 1][r] = v.y;
    tile[cx * 4 + 2][r] = v.z;
    tile[cx * 4 + 3][r] = v.w;
  }
  __syncthreads();
  const int rq = threadIdx.x & 15, cy = threadIdx.x >> 4;
#pragma unroll
  for (int i = 0; i < 4; ++i) {
    const int c = cy + i * 16;
    ushort4 o;
    o.x = f2bf(tile[c][rq * 4 + 0]);
    o.y = f2bf(tile[c][rq * 4 + 1]);
    o.z = f2bf(tile[c][rq * 4 + 2]);
    o.w = f2bf(tile[c][rq * 4 + 3]);
    *(ushort4*)&out[(size_t)(c0 + c) * R + r0 + rq * 4] = o;
  }
}

// ---------------------------------------------------------------------------
// Templated MFMA GEMM core: C tile (MR*32) x (NR*32), BK=64, 4 waves 2x2
// (per-wave MR*16 x NR*16). Proven 2-phase structure: double-buffered LDS,
// issue-early stage, one __syncthreads per K-step, chunk-XOR swizzle
// (conflicts measured 0). Smaller tiles = more blocks = higher residency;
// m102/m97 residency curve: 2.5 blk/CU -> 469 TF, 3/CU -> 874 TF.
template<int MR, int NR>
__device__ __forceinline__ void gemm_core_t(
    const ushort* __restrict__ A, const ushort* __restrict__ Bt,
    int row0, int col0, ushort* As, ushort* Bs, f32x4 (&acc)[MR][NR])
{
  const int tid = threadIdx.x;
  const int w = tid >> 6, l = tid & 63, lq = l >> 4, lm = l & 15;
  const int wr = (w >> 1) * (MR * 16), wc = (w & 1) * (NR * 16);
  const int sx = lm & 7;                               // read-swizzle key
  const int gsw = (tid & 7) ^ ((tid >> 3) & 7);        // pre-swizzled source chunk
  const ushort* Ag = A + (size_t)(row0 + (tid >> 3)) * WD_ + gsw * 8;
  const ushort* Bg = Bt + (size_t)(col0 + (tid >> 3)) * WD_ + gsw * 8;
  constexpr int ABUF = MR * 2048;   // ushorts per A buffer (MR*32 rows x 64)
  constexpr int BBUF = NR * 2048;
  AS3 ushort* AsW = (AS3 ushort*)As + w * 512;   // wave w: rows c*32 + w*8
  AS3 ushort* BsW = (AS3 ushort*)Bs + w * 512;

  auto stage = [&](int buf, int k0) {
#pragma unroll
    for (int c = 0; c < MR; ++c)
      g2l16(Ag + (size_t)(c * 32) * WD_ + k0, AsW + buf * ABUF + c * 2048);
#pragma unroll
    for (int c = 0; c < NR; ++c)
      g2l16(Bg + (size_t)(c * 32) * WD_ + k0, BsW + buf * BBUF + c * 2048);
  };

  stage(0, 0);
  __syncthreads();           // prologue: tile 0 resident
  int buf = 0;
  for (int k0 = 0; k0 < WD_; k0 += 64) {
    if (k0 + 64 < WD_) stage(buf ^ 1, k0 + 64);   // issue early, fly under compute
    const ushort* Ab = As + buf * ABUF;
    const ushort* Bb = Bs + buf * BBUF;
#pragma unroll
    for (int kk = 0; kk < 2; ++kk) {
      short8 af[MR], bfr[NR];
#pragma unroll
      for (int mi = 0; mi < MR; ++mi)
        af[mi] = *(const short8*)&Ab[(wr + mi * 16 + lm) * 64 + (((kk * 4 + lq) ^ sx) << 3)];
#pragma unroll
      for (int ni = 0; ni < NR; ++ni)
        bfr[ni] = *(const short8*)&Bb[(wc + ni * 16 + lm) * 64 + (((kk * 4 + lq) ^ sx) << 3)];
#pragma unroll
      for (int mi = 0; mi < MR; ++mi)
#pragma unroll
        for (int ni = 0; ni < NR; ++ni)
          acc[mi][ni] = __builtin_amdgcn_mfma_f32_16x16x32_bf16(af[mi], bfr[ni], acc[mi][ni], 0, 0, 0);
    }
    __syncthreads();         // next buf ready, reads done
    buf ^= 1;
  }
}

// ---------------------------------------------------------------------------
// All projections, 128x64 tiles. grid (80, 16) = 1280 blocks -> 3 blocks/CU
// resident (48 KiB LDS), 5 queued.
//  bx<64: qg (bf16, ldc 4096) | bx 64..71: k->kcache f32 | bx 72..79: v->vcache
__global__ __launch_bounds__(256) void gemm_proj(
    const ushort* __restrict__ A,
    const ushort* __restrict__ qg0t, const ushort* __restrict__ qg1t,
    const ushort* __restrict__ k0t,  const ushort* __restrict__ k1t,
    const ushort* __restrict__ v0t,  const ushort* __restrict__ v1t,
    ushort* __restrict__ Cqg, float* __restrict__ kc, float* __restrict__ vc)
{
  __shared__ ushort As[2 * 8192], Bs[2 * 4096];
  const int bx = blockIdx.x;
  const int row0 = blockIdx.y * 128;
  const bool s1 = (row0 >= T0_);
  const ushort* Bt; int col0;
  float* Cf = nullptr; ushort* Cb = nullptr; int ldc;
  if (bx < 64) {
    Bt = s1 ? qg1t : qg0t; col0 = bx * 64; Cb = Cqg; ldc = 4096;
  } else if (bx < 72) {
    Bt = s1 ? k1t : k0t; col0 = (bx - 64) * 64; Cf = kc; ldc = 512;
  } else {
    Bt = s1 ? v1t : v0t; col0 = (bx - 72) * 64; Cf = vc; ldc = 512;
  }
  f32x4 acc[4][2];
#pragma unroll
  for (int mi = 0; mi < 4; ++mi)
#pragma unroll
    for (int ni = 0; ni < 2; ++ni) acc[mi][ni] = (f32x4){0.f, 0.f, 0.f, 0.f};
  gemm_core_t<4, 2>(A, Bt, row0, col0, As, Bs, acc);
  const int w = threadIdx.x >> 6, l = threadIdx.x & 63, lq = l >> 4, lm = l & 15;
  const int wr = (w >> 1) * 64, wc = (w & 1) * 32;
#pragma unroll
  for (int mi = 0; mi < 4; ++mi)
#pragma unroll
    for (int ni = 0; ni < 2; ++ni)
#pragma unroll
      for (int r = 0; r < 4; ++r) {
        const size_t rr = (size_t)row0 + wr + mi * 16 + lq * 4 + r;
        const size_t cc = (size_t)col0 + wc + ni * 16 + lm;
        if (Cb) Cb[rr * ldc + cc] = f2bf(acc[mi][ni][r]);
        else    Cf[rr * ldc + cc] = acc[mi][ni][r];
      }
}

// ---------------------------------------------------------------------------
// out projection, 128x64 tiles: grid (32, 16). C f32 (t, 2048), weight by stream.
__global__ __launch_bounds__(256) void gemm_out(
    const ushort* __restrict__ A, const ushort* __restrict__ W0t,
    const ushort* __restrict__ W1t, float* __restrict__ C)
{
  __shared__ ushort As[2 * 8192], Bs[2 * 4096];
  const int row0 = blockIdx.y * 128, col0 = blockIdx.x * 64;
  const ushort* Bt = (row0 < T0_) ? W0t : W1t;
  f32x4 acc[4][2];
#pragma unroll
  for (int mi = 0; mi < 4; ++mi)
#pragma unroll
    for (int ni = 0; ni < 2; ++ni) acc[mi][ni] = (f32x4){0.f, 0.f, 0.f, 0.f};
  gemm_core_t<4, 2>(A, Bt, row0, col0, As, Bs, acc);
  const int w = threadIdx.x >> 6, l = threadIdx.x & 63, lq = l >> 4, lm = l & 15;
  const int wr = (w >> 1) * 64, wc = (w & 1) * 32;
#pragma unroll
  for (int mi = 0; mi < 4; ++mi)
#pragma unroll
    for (int ni = 0; ni < 2; ++ni)
#pragma unroll
      for (int r = 0; r < 4; ++r) {
        const size_t rr = (size_t)row0 + wr + mi * 16 + lq * 4 + r;
        const size_t cc = (size_t)col0 + wc + ni * 16 + lm;
        C[rr * 2048 + cc] = acc[mi][ni][r];
      }
}

// ---------------------------------------------------------------------------
// Fused: RMSNorm + RoPE (+ q scale)  [blocks 0..2047]
//        V transpose vcache f32 (2048,512) -> Vtb bf16 (512,2048)  [2048..2303]
__global__ __launch_bounds__(256) void postproc_vt(
    ushort* __restrict__ qgb, float* __restrict__ kc, ushort* __restrict__ Kb,
    const int* __restrict__ positions,
    const float* __restrict__ qn0, const float* __restrict__ kn0,
    const float* __restrict__ qn1, const float* __restrict__ kn1,
    const float* __restrict__ vcache, ushort* __restrict__ Vtb)
{
  __shared__ float tile[64][67];
  if (blockIdx.x >= 2048) {
    const int idx = blockIdx.x - 2048;           // 32 r-tiles x 8 c-tiles
    const int r0 = (idx & 31) * 64, c0 = (idx >> 5) * 64;
    const int cx = threadIdx.x & 15, ry = threadIdx.x >> 4;
#pragma unroll
    for (int i = 0; i < 4; ++i) {
      const int r = ry + i * 16;
      const float4 v = *(const float4*)&vcache[(size_t)(r0 + r) * 512 + c0 + cx * 4];
      tile[cx * 4 + 0][r] = v.x;
      tile[cx * 4 + 1][r] = v.y;
      tile[cx * 4 + 2][r] = v.z;
      tile[cx * 4 + 3][r] = v.w;
    }
    __syncthreads();
    const int rq = threadIdx.x & 15, cy = threadIdx.x >> 4;
#pragma unroll
    for (int i = 0; i < 4; ++i) {
      const int c = cy + i * 16;
      ushort4 o;
      o.x = f2bf(tile[c][rq * 4 + 0]);
      o.y = f2bf(tile[c][rq * 4 + 1]);
      o.z = f2bf(tile[c][rq * 4 + 2]);
      o.w = f2bf(tile[c][rq * 4 + 3]);
      *(ushort4*)&Vtb[(size_t)(c0 + c) * 2048 + r0 + rq * 4] = o;
    }
    return;
  }
  const int t = blockIdx.x;
  const int w = threadIdx.x >> 6, l = threadIdx.x & 63;
  const float pos = (float)positions[t];
  const bool str1 = (t >= T0_);
  const float* qn = str1 ? qn1 : qn0;
  const float* kn = str1 ? kn1 : kn0;
  const float kfreq = 13.815510557964274f / 32.0f;  // ln(1e6)/32
  const int h0 = 2 * l, h1 = 2 * l + 1;

  for (int r = w; r < NH_ + KH_; r += 4) {
    const bool isq = (r < NH_);
    float v0, v1; size_t bi; const float* sc;
    if (isq) {
      bi = ((size_t)t * NH_ + r) * 256;
      v0 = bf2f(qgb[bi + h0]); v1 = bf2f(qgb[bi + h1]); sc = qn;
    } else {
      bi = ((size_t)t * KH_ + (r - NH_)) * 128;
      v0 = kc[bi + h0]; v1 = kc[bi + h1]; sc = kn;
    }
    float ss = v0 * v0 + v1 * v1;
#pragma unroll
    for (int off = 32; off > 0; off >>= 1) ss += __shfl_xor(ss, off);
    const float rstd = rsqrtf(ss * (1.0f / 128.0f) + 1e-6f);
    v0 = v0 * rstd * (1.0f + sc[h0]);
    v1 = v1 * rstd * (1.0f + sc[h1]);
    const float p0 = __shfl_xor(v0, 16);
    const float p1 = __shfl_xor(v1, 16);
    if (l < 32) {
      const int i0 = (l < 16) ? h0 : (h0 - 32);
      const float a0 = pos * __expf(-(float)i0 * kfreq);
      const float a1 = pos * __expf(-(float)(i0 + 1) * kfreq);
      const float c0 = cosf(a0), s0 = sinf(a0);
      const float c1 = cosf(a1), s1v = sinf(a1);
      if (l < 16) { v0 = v0 * c0 - p0 * s0; v1 = v1 * c1 - p1 * s1v; }
      else        { v0 = v0 * c0 + p0 * s0; v1 = v1 * c1 + p1 * s1v; }
    }
    if (isq) {
      v0 *= 0.08838834764831843f; v1 *= 0.08838834764831843f;
      qgb[bi + h0] = f2bf(v0); qgb[bi + h1] = f2bf(v1);
    } else {
      kc[bi + h0] = v0; kc[bi + h1] = v1;
      Kb[bi + h0] = f2bf(v0); Kb[bi + h1] = f2bf(v1);
    }
  }
}

// ---------------------------------------------------------------------------
// Flash attention, S^T formulation, XOR-swizzled LDS. SB=64 s-step ->
// LDS 72 KiB -> 2 blocks/CU. Grid (32, 16): one qt tile per block,
// qt = (n<8) ? bx : 31-bx so co-scheduled block pairs sum to ~equal work.
__global__ __launch_bounds__(256) void attn(
    const ushort* __restrict__ qgb, const ushort* __restrict__ Kb,
    const ushort* __restrict__ Vt, ushort* __restrict__ encb)
{
  __shared__ ushort Ks[2 * 8192];  // [buf][s 0..63][h 0..127], 16B chunks ^ (s&15)
  __shared__ ushort Vs[2 * 8192];  // [buf][h 0..127][s 0..63],  16B chunks ^ (h&7)
  __shared__ ushort Ps[4 * 1024];  // per-wave [q 0..15][s 0..63], 8B units ^ lm
  const int tid = threadIdx.x;
  const int w = tid >> 6, l = tid & 63, lq = l >> 4, lm = l & 15;
  const int n = blockIdx.y, kh = n >> 2;
  const int qt = (n < 8) ? (int)blockIdx.x : (31 - (int)blockIdx.x);
  const int qtb = qt * 64;
  const int nst = qt + 1;          // 64-wide s-steps

  auto stage = [&](int buf, int s0) {
#pragma unroll
    for (int c = 0; c < 4; ++c) {
      {
        const int base = c * 16 + w * 4;          // K s-row base
        const int row = base + (l >> 4);
        const int j = l & 15;
        g2l16(Kb + (size_t)(s0 + row) * 512 + kh * 128 + (j ^ (row & 15)) * 8,
              (AS3 ushort*)Ks + buf * 8192 + base * 128);
      }
      {
        const int base = c * 32 + w * 8;          // V h-row base
        const int row = base + (l >> 3);
        const int j = l & 7;
        g2l16(Vt + (size_t)(kh * 128 + row) * 2048 + s0 + (j ^ (row & 7)) * 8,
              (AS3 ushort*)Vs + buf * 8192 + base * 64);
      }
    }
  };

  short8 aq[4];
  {
    const ushort* qb = qgb + ((size_t)(qtb + w * 16 + lm) * NH_ + n) * 256 + lq * 8;
#pragma unroll
    for (int kk = 0; kk < 4; ++kk) aq[kk] = *(const short8*)(qb + kk * 32);
  }
  f32x4 acc[8];
#pragma unroll
  for (int i = 0; i < 8; ++i) acc[i] = (f32x4){0.f, 0.f, 0.f, 0.f};
  float mq = -3.0e38f, lsum = 0.0f;

  stage(0, 0);

  for (int st = 0; st < nst; ++st) {
    const int buf = st & 1;
    const int s0 = st * 64;
    __syncthreads();
    if (st + 1 < nst) stage(buf ^ 1, s0 + 64);
    const ushort* Kt = Ks + buf * 8192;
    const ushort* Vb = Vs + buf * 8192;

    // S^T = K * Q^T : D[m=s][n=q]
    f32x4 sa[4];
#pragma unroll
    for (int mi = 0; mi < 4; ++mi) sa[mi] = (f32x4){0.f, 0.f, 0.f, 0.f};
#pragma unroll
    for (int kk = 0; kk < 4; ++kk)
#pragma unroll
      for (int mi = 0; mi < 4; ++mi) {
        const short8 ak = *(const short8*)&Kt[(mi * 16 + lm) * 128 + ((kk * 4 + lq) ^ lm) * 8];
        sa[mi] = __builtin_amdgcn_mfma_f32_16x16x32_bf16(ak, aq[kk], sa[mi], 0, 0, 0);
      }
    if (s0 + 63 > qtb) {
      const int qg_ = qtb + w * 16 + lm;
#pragma unroll
      for (int mi = 0; mi < 4; ++mi)
#pragma unroll
        for (int r = 0; r < 4; ++r)
          if (s0 + mi * 16 + lq * 4 + r > qg_) sa[mi][r] = -3.0e38f;
    }
    float mx = sa[0][0];
#pragma unroll
    for (int mi = 0; mi < 4; ++mi)
#pragma unroll
      for (int r = 0; r < 4; ++r) mx = fmaxf(mx, sa[mi][r]);
    mx = fmaxf(mx, __shfl_xor(mx, 16));
    mx = fmaxf(mx, __shfl_xor(mx, 32));
    const float mn = fmaxf(mq, mx);
    const float alpha = __expf(mq - mn);
    mq = mn;
    float sl = 0.0f;
#pragma unroll
    for (int mi = 0; mi < 4; ++mi)
#pragma unroll
      for (int r = 0; r < 4; ++r) {
        const float p = __expf(sa[mi][r] - mn);
        sa[mi][r] = p; sl += p;
      }
    sl += __shfl_xor(sl, 16);
    sl += __shfl_xor(sl, 32);
    lsum = lsum * alpha + sl;

#pragma unroll
    for (int mi = 0; mi < 4; ++mi) {
      short4v pw;
#pragma unroll
      for (int r = 0; r < 4; ++r) pw[r] = (short)f2bf(sa[mi][r]);
      *(short4v*)&Ps[w * 1024 + lm * 64 + ((mi * 4 + lq) ^ lm) * 4] = pw;
    }
    float aP[4];
#pragma unroll
    for (int r = 0; r < 4; ++r) aP[r] = __shfl(alpha, lq * 4 + r);
#pragma unroll
    for (int hi = 0; hi < 8; ++hi) {
      f32x4 a = acc[hi];
#pragma unroll
      for (int r = 0; r < 4; ++r) a[r] *= aP[r];
      acc[hi] = a;
    }
#pragma unroll
    for (int mi2 = 0; mi2 < 2; ++mi2) {
      const short4v pa = *(const short4v*)&Ps[w * 1024 + lm * 64 + ((mi2 * 8 + lq * 2 + 0) ^ lm) * 4];
      const short4v pb = *(const short4v*)&Ps[w * 1024 + lm * 64 + ((mi2 * 8 + lq * 2 + 1) ^ lm) * 4];
      const short8 ap = __builtin_shufflevector(pa, pb, 0, 1, 2, 3, 4, 5, 6, 7);
#pragma unroll
      for (int hi = 0; hi < 8; ++hi) {
        const short8 bv = *(const short8*)&Vb[(hi * 16 + lm) * 64 + (((mi2 * 4 + lq) ^ (lm & 7)) << 3)];
        acc[hi] = __builtin_amdgcn_mfma_f32_16x16x32_bf16(ap, bv, acc[hi], 0, 0, 0);
      }
    }
  }
  const float linv = 1.0f / lsum;
  float lP[4];
#pragma unroll
  for (int r = 0; r < 4; ++r) lP[r] = __shfl(linv, lq * 4 + r);
#pragma unroll
  for (int hi = 0; hi < 8; ++hi)
#pragma unroll
    for (int r = 0; r < 4; ++r) {
      const int t = qtb + w * 16 + lq * 4 + r;
      const int h = hi * 16 + lm;
      const float g = bf2f(qgb[((size_t)t * NH_ + n) * 256 + 128 + h]);
      const float o = acc[hi][r] * lP[r] * (1.0f / (1.0f + __expf(-g)));
      encb[((size_t)t * NH_ + n) * 128 + h] = f2bf(o);
    }
}

// ---------------------------------------------------------------------------
extern "C" void kernel_launch(void* const* d_in, const int* in_sizes, int n_in,
                              void* d_out, int out_size, void* d_ws, size_t ws_size,
                              hipStream_t stream)
{
  (void)in_sizes; (void)n_in; (void)out_size; (void)ws_size;
  const float* x0    = (const float*)d_in[0];
  const float* x1    = (const float*)d_in[1];
  const int*   pos   = (const int*)d_in[2];
  const float* qg_w0 = (const float*)d_in[4];
  const float* k_w0  = (const float*)d_in[5];
  const float* v_w0  = (const float*)d_in[6];
  const float* qn0   = (const float*)d_in[7];
  const float* kn0   = (const float*)d_in[8];
  const float* o_w0  = (const float*)d_in[9];
  const float* qg_w1 = (const float*)d_in[10];
  const float* k_w1  = (const float*)d_in[11];
  const float* v_w1  = (const float*)d_in[12];
  const float* qn1   = (const float*)d_in[13];
  const float* kn1   = (const float*)d_in[14];
  const float* o_w1  = (const float*)d_in[15];

  float* out    = (float*)d_out;
  float* kcache = out + (size_t)TT_ * WD_;
  float* vcache = kcache + (size_t)TT_ * KH_ * 128;
  ushort* qsc = (ushort*)d_out;  // out0/out1 region doubles as qg_w0^T scratch

  // ws: wbuf 16M | xb 8M (-> Kb 2M + Vt 2M after projections) | qgb 16M | encb 8M
  ushort* wbuf = (ushort*)d_ws;
  ushort* xb   = wbuf + 8388608;
  ushort* qgb  = xb + 4194304;
  ushort* encb = qgb + 8388608;
  ushort* Kbuf = xb;
  ushort* Vtb  = xb + 1048576;
  ushort* k0t = encb, *k1t = encb + 1048576, *v0t = encb + 2097152, *v1t = encb + 3145728;

  // merged convert + qg/k/v transposes
  prep<<<9216, 256, 0, stream>>>(x0, x1, xb,
                                 qg_w0, qg_w1, qsc, wbuf,
                                 k_w0, k_w1, k0t, k1t,
                                 v_w0, v_w1, v0t, v1t);

  // all projections, one launch (128x64 tiles, 1280 blocks)
  gemm_proj<<<dim3(80, 16), 256, 0, stream>>>(xb, qsc, wbuf, k0t, k1t, v0t, v1t,
                                              qgb, kcache, vcache);

  // norm + rope + fused V transpose
  postproc_vt<<<2304, 256, 0, stream>>>(qgb, kcache, Kbuf, pos, qn0, kn0, qn1, kn1,
                                        vcache, Vtb);

  attn<<<dim3(32, 16), 256, 0, stream>>>(qgb, Kbuf, Vtb, encb);

  // output projection
  convtrans64<<<dim3(32, 32, 2), 256, 0, stream>>>(o_w0, o_w1, wbuf, wbuf + 4194304, WD_, WD_, 1);
  gemm_out<<<dim3(32, 16), 256, 0, stream>>>(encb, wbuf, wbuf + 4194304, out);
}